// Round 1
// baseline (2905.658 us; speedup 1.0000x reference)
//
#include <hip/hip_runtime.h>
#include <math.h>

#define Lq 512
#define CSd 256
#define CZd 128
#define Hd 8
#define CHd 32
#define PQd 4
#define PVd 8
#define CATd 1536
#define NPROJ 1152

// ---------------- ws layout (float offsets) ----------------
#define OFF_S0      0
#define OFF_SC      131072
#define OFF_WCAT    262144
#define OFF_BCAT    557056
#define OFF_MURS    558208
#define OFF_PB      1082496
#define OFF_P       3179648
#define OFF_QPG     3769472
#define OFF_KPG     3818624
#define OFF_VPG     3867776
#define OFF_QN      3966080
#define OFF_KN      3970176
#define OFF_A       3974272
#define OFF_CAT     6071424
#define OFF_OPTG    6857856
#define OFF_IPA     6956160
#define OFF_TR1     7087232
#define OFF_TR2     7218304
#define OFF_TR3     7349376
#define OFF_R       7480448
#define OFF_T       7485056
#define OFF_UPD     7486592
#define OFF_GAMMA   7489664
#define OFF_MASKB   7489672

__device__ __forceinline__ float wave_sum(float v){
  #pragma unroll
  for (int m=32; m; m>>=1) v += __shfl_xor(v, m);
  return v;
}
__device__ __forceinline__ float wave_max(float v){
  #pragma unroll
  for (int m=32; m; m>>=1) v = fmaxf(v, __shfl_xor(v, m));
  return v;
}

// ------------- setup: Wcat/bcat/gamma/maskbias/R/t -------------
__global__ __launch_bounds__(256) void k_setup(
    const float* __restrict__ wq, const float* __restrict__ wk, const float* __restrict__ wv,
    const float* __restrict__ wqp, const float* __restrict__ wkp, const float* __restrict__ wvp,
    const float* __restrict__ bq, const float* __restrict__ bk, const float* __restrict__ bv,
    const float* __restrict__ bqp, const float* __restrict__ bkp, const float* __restrict__ bvp,
    const float* __restrict__ head_w, const float* __restrict__ mask,
    float* __restrict__ Wcat, float* __restrict__ bcat, float* __restrict__ gamma,
    float* __restrict__ maskb, float* __restrict__ R, float* __restrict__ t){
  int idx = blockIdx.x*256 + threadIdx.x;
  if (idx < CSd*NPROJ){
    int r = idx / NPROJ, c = idx % NPROJ;
    float v;
    if      (c < 256) v = wq[r*256 + c];
    else if (c < 512) v = wk[r*256 + c-256];
    else if (c < 768) v = wv[r*256 + c-512];
    else if (c < 864) v = wqp[r*96 + c-768];
    else if (c < 960) v = wkp[r*96 + c-864];
    else              v = wvp[r*192 + c-960];
    Wcat[idx] = v;
    return;
  }
  int k = idx - CSd*NPROJ;
  if (k < NPROJ){
    float v;
    if      (k < 256) v = bq[k];
    else if (k < 512) v = bk[k-256];
    else if (k < 768) v = bv[k-512];
    else if (k < 864) v = bqp[k-768];
    else if (k < 960) v = bkp[k-864];
    else              v = bvp[k-960];
    bcat[k] = v;
    return;
  }
  k -= NPROJ;
  if (k < Hd){ gamma[k] = log1pf(expf(head_w[k])); return; }
  k -= Hd;
  if (k < Lq){ maskb[k] = (mask[k] - 1.f)*1e9f; return; }
  k -= Lq;
  if (k < Lq){
    #pragma unroll
    for (int ii=0; ii<9; ii++) R[k*9+ii] = (ii==0||ii==4||ii==8) ? 1.f : 0.f;
    t[k*3] = 0.f; t[k*3+1] = 0.f; t[k*3+2] = 0.f;
  }
}

// ------------- LN over CS=256 row (optionally add y first) -------------
__global__ __launch_bounds__(256) void k_addln(
    const float* __restrict__ x, const float* __restrict__ y,
    const float* __restrict__ g, const float* __restrict__ b,
    float* __restrict__ out){
  __shared__ float red[4];
  int row = blockIdx.x, tid = threadIdx.x;
  float v = x[row*CSd + tid];
  if (y) v += y[row*CSd + tid];
  int wid = tid>>6, lane = tid&63;
  float s = wave_sum(v);
  if (lane==0) red[wid] = s;
  __syncthreads();
  float mu = (red[0]+red[1]+red[2]+red[3]) * (1.f/CSd);
  __syncthreads();
  float d = v - mu;
  float s2 = wave_sum(d*d);
  if (lane==0) red[wid] = s2;
  __syncthreads();
  float var = (red[0]+red[1]+red[2]+red[3]) * (1.f/CSd);
  float rs = rsqrtf(var + 1e-5f);
  out[row*CSd + tid] = d*rs*g[tid] + b[tid];
}

// ------------- zn stats (mu,rs) + pair_bias; wave per (i,j) row -------------
__global__ __launch_bounds__(256) void k_lnz_pb(
    const float* __restrict__ z, const float* __restrict__ g, const float* __restrict__ b,
    const float* __restrict__ wpb, float* __restrict__ murs, float* __restrict__ pb){
  int tid = threadIdx.x, wid = tid>>6, lane = tid&63;
  int row = blockIdx.x*4 + wid;                // (i*512 + j)
  const float* zr = z + (size_t)row*CZd;
  float2 zv = ((const float2*)zr)[lane];
  float2 gv = ((const float2*)g)[lane];
  float2 bv = ((const float2*)b)[lane];
  float mu = wave_sum(zv.x + zv.y) * (1.f/CZd);
  float dx = zv.x - mu, dy = zv.y - mu;
  float var = wave_sum(dx*dx + dy*dy) * (1.f/CZd);
  float rs = rsqrtf(var + 1e-5f);
  if (lane==0){ murs[row*2] = mu; murs[row*2+1] = rs; }
  float zn0 = dx*rs*gv.x + bv.x;
  float zn1 = dy*rs*gv.y + bv.y;
  int c0 = lane*2, c1 = lane*2+1;
  int i = row >> 9, j = row & 511;
  #pragma unroll
  for (int h=0; h<Hd; h++){
    float p = zn0*wpb[c0*Hd+h] + zn1*wpb[c1*Hd+h];
    p = wave_sum(p);
    if (lane==0) pb[((size_t)(h*Lq + i))*Lq + j] = p;
  }
}

// ------------- generic tiled fp32 GEMM: C[512,N] = A[512,K]@W[K,N] + bias -------------
template<int TM>
__global__ __launch_bounds__(256) void k_gemm(
    const float* __restrict__ A, int lda,
    const float* __restrict__ W, int ldw,
    const float* __restrict__ B,
    float* __restrict__ C, int ldc,
    int K, int relu, const float* __restrict__ rowscale){
  __shared__ float At[TM][36];
  __shared__ float Bt[32][64];
  const int tid = threadIdx.x;
  const int n0 = blockIdx.x*64, m0 = blockIdx.y*TM;
  const int c4 = (tid & 15)*4;
  const int rg = tid >> 4;            // 0..15
  const int RPT = TM/16;              // 2 (TM=32) or 1 (TM=16)
  float4 acc[RPT];
  #pragma unroll
  for (int r=0; r<RPT; r++) acc[r] = make_float4(0.f,0.f,0.f,0.f);
  for (int k0=0; k0<K; k0+=32){
    for (int idx=tid; idx < TM*8; idx+=256){
      int r = idx>>3, q = idx&7;
      float4 v = ((const float4*)&A[(size_t)(m0+r)*lda + k0])[q];
      At[r][q*4]   = v.x; At[r][q*4+1] = v.y;
      At[r][q*4+2] = v.z; At[r][q*4+3] = v.w;
    }
    for (int idx=tid; idx < 512; idx+=256){
      int r = idx>>4, q = idx&15;
      float4 v = ((const float4*)&W[(size_t)(k0+r)*ldw + n0])[q];
      *(float4*)&Bt[r][q*4] = v;
    }
    __syncthreads();
    #pragma unroll
    for (int kk=0; kk<32; kk++){
      float4 bv = *(const float4*)&Bt[kk][c4];
      #pragma unroll
      for (int r=0; r<RPT; r++){
        float av = At[rg*RPT + r][kk];
        acc[r].x += av*bv.x; acc[r].y += av*bv.y;
        acc[r].z += av*bv.z; acc[r].w += av*bv.w;
      }
    }
    __syncthreads();
  }
  #pragma unroll
  for (int r=0; r<RPT; r++){
    int m = m0 + rg*RPT + r;
    float4 v = acc[r];
    if (B){ v.x += B[n0+c4]; v.y += B[n0+c4+1]; v.z += B[n0+c4+2]; v.w += B[n0+c4+3]; }
    if (relu){ v.x=fmaxf(v.x,0.f); v.y=fmaxf(v.y,0.f); v.z=fmaxf(v.z,0.f); v.w=fmaxf(v.w,0.f); }
    if (rowscale){ float ms = rowscale[m]; v.x*=ms; v.y*=ms; v.z*=ms; v.w*=ms; }
    *(float4*)&C[(size_t)m*ldc + n0 + c4] = v;
  }
}

// ------------- apply frame R,t to qp/kp/vp; compute qn/kn -------------
__global__ __launch_bounds__(256) void k_proj_frame(
    const float* __restrict__ P, const float* __restrict__ R, const float* __restrict__ t,
    float* __restrict__ qpg, float* __restrict__ kpg, float* __restrict__ vpg,
    float* __restrict__ qn, float* __restrict__ kn){
  int idx = blockIdx.x*256 + threadIdx.x;   // 4096 = L*H
  int l = idx >> 3, h = idx & 7;
  float Rm[9], tv[3];
  #pragma unroll
  for (int ii=0; ii<9; ii++) Rm[ii] = R[l*9+ii];
  #pragma unroll
  for (int ii=0; ii<3; ii++) tv[ii] = t[l*3+ii];
  const float* row = P + (size_t)l*NPROJ;
  float accq = 0.f;
  #pragma unroll
  for (int p=0; p<PQd; p++){
    float x0 = row[768 + h*12 + p*3], x1 = row[768 + h*12 + p*3+1], x2 = row[768 + h*12 + p*3+2];
    float g0 = Rm[0]*x0 + Rm[1]*x1 + Rm[2]*x2 + tv[0];
    float g1 = Rm[3]*x0 + Rm[4]*x1 + Rm[5]*x2 + tv[1];
    float g2 = Rm[6]*x0 + Rm[7]*x1 + Rm[8]*x2 + tv[2];
    int o = (l*Hd + h)*12 + p*3;
    qpg[o] = g0; qpg[o+1] = g1; qpg[o+2] = g2;
    accq += g0*g0 + g1*g1 + g2*g2;
  }
  qn[l*Hd + h] = accq;
  float acck = 0.f;
  #pragma unroll
  for (int p=0; p<PQd; p++){
    float x0 = row[864 + h*12 + p*3], x1 = row[864 + h*12 + p*3+1], x2 = row[864 + h*12 + p*3+2];
    float g0 = Rm[0]*x0 + Rm[1]*x1 + Rm[2]*x2 + tv[0];
    float g1 = Rm[3]*x0 + Rm[4]*x1 + Rm[5]*x2 + tv[1];
    float g2 = Rm[6]*x0 + Rm[7]*x1 + Rm[8]*x2 + tv[2];
    int o = (l*Hd + h)*12 + p*3;
    kpg[o] = g0; kpg[o+1] = g1; kpg[o+2] = g2;
    acck += g0*g0 + g1*g1 + g2*g2;
  }
  kn[l*Hd + h] = acck;
  #pragma unroll
  for (int p=0; p<PVd; p++){
    float x0 = row[960 + h*24 + p*3], x1 = row[960 + h*24 + p*3+1], x2 = row[960 + h*24 + p*3+2];
    float g0 = Rm[0]*x0 + Rm[1]*x1 + Rm[2]*x2 + tv[0];
    float g1 = Rm[3]*x0 + Rm[4]*x1 + Rm[5]*x2 + tv[1];
    float g2 = Rm[6]*x0 + Rm[7]*x1 + Rm[8]*x2 + tv[2];
    int o = (l*Hd + h)*24 + p*3;
    vpg[o] = g0; vpg[o+1] = g1; vpg[o+2] = g2;
  }
}

// ------------- logits: per-head 32x64 tiles -------------
__global__ __launch_bounds__(256) void k_logits(
    const float* __restrict__ P, const float* __restrict__ qpg, const float* __restrict__ kpg,
    const float* __restrict__ qn, const float* __restrict__ kn, const float* __restrict__ pb,
    const float* __restrict__ gamma, const float* __restrict__ maskb, float* __restrict__ abuf){
  __shared__ float Qt[32][33];
  __shared__ float QPt[32][12];
  __shared__ float Kt[64][33];
  __shared__ float KPt[64][13];
  int tid = threadIdx.x;
  int j0 = blockIdx.x*64, i0 = blockIdx.y*32, h = blockIdx.z;
  for (int idx=tid; idx<1024; idx+=256){ int r=idx>>5, cc=idx&31; Qt[r][cc] = P[(size_t)(i0+r)*NPROJ + h*CHd + cc]; }
  for (int idx=tid; idx<384;  idx+=256){ int r=idx/12, cc=idx%12; QPt[r][cc] = qpg[((i0+r)*Hd+h)*12 + cc]; }
  for (int idx=tid; idx<2048; idx+=256){ int r=idx>>5, cc=idx&31; Kt[r][cc] = P[(size_t)(j0+r)*NPROJ + 256 + h*CHd + cc]; }
  for (int idx=tid; idx<768;  idx+=256){ int r=idx/12, cc=idx%12; KPt[r][cc] = kpg[((j0+r)*Hd+h)*12 + cc]; }
  __syncthreads();
  int j = tid & 63, ib = tid >> 6;
  float knj = kn[(j0+j)*Hd + h];
  float mb  = maskb[j0+j];
  float gam = gamma[h];
  const float wL = 0.57735026918962576f;   // sqrt(1/3)
  const float wC = 0.23570226039551584f;   // sqrt(2/(9*PQ)) = sqrt(1/18)
  const float iS = 0.17677669529663687f;   // 1/sqrt(32)
  #pragma unroll
  for (int r=0; r<8; r++){
    int i = ib*8 + r;
    float scal = 0.f, qk = 0.f;
    #pragma unroll
    for (int cc=0; cc<32; cc++) scal += Qt[i][cc]*Kt[j][cc];
    #pragma unroll
    for (int cc=0; cc<12; cc++) qk += QPt[i][cc]*KPt[j][cc];
    float d2 = qn[(i0+i)*Hd + h] + knj - 2.f*qk;
    float lg = wL*(scal*iS + pb[((size_t)(h*Lq + i0+i))*Lq + j0 + j] - 0.5f*wC*gam*d2) + mb;
    abuf[((size_t)(h*Lq + i0+i))*Lq + j0 + j] = lg;
  }
}

// ------------- row softmax over 512 -------------
__global__ __launch_bounds__(256) void k_softmax(float* __restrict__ abuf){
  __shared__ float red[4];
  int row = blockIdx.x, tid = threadIdx.x;
  float* base = abuf + (size_t)row*Lq;
  float v0 = base[tid], v1 = base[tid+256];
  int wid = tid>>6, lane = tid&63;
  float m = wave_max(fmaxf(v0, v1));
  if (lane==0) red[wid] = m;
  __syncthreads();
  m = fmaxf(fmaxf(red[0],red[1]), fmaxf(red[2],red[3]));
  __syncthreads();
  float e0 = __expf(v0-m), e1 = __expf(v1-m);
  float s = wave_sum(e0+e1);
  if (lane==0) red[wid] = s;
  __syncthreads();
  s = red[0]+red[1]+red[2]+red[3];
  float inv = 1.f/s;
  base[tid] = e0*inv; base[tid+256] = e1*inv;
}

// ------------- o = a@v and optg = a@vpg -------------
__global__ __launch_bounds__(256) void k_av(
    const float* __restrict__ abuf, const float* __restrict__ P, const float* __restrict__ vpg,
    float* __restrict__ cat, float* __restrict__ optg){
  __shared__ float At[16][33];
  __shared__ float Vt[33][57];
  int tid = threadIdx.x;
  int i0 = blockIdx.x*16, h = blockIdx.y;
  int c = tid & 63, r4 = tid >> 6;
  float acc[4] = {0.f,0.f,0.f,0.f};
  for (int j0=0; j0<Lq; j0+=32){
    for (int idx=tid; idx<512; idx+=256){ int r=idx>>5, jj=idx&31; At[r][jj] = abuf[((size_t)(h*Lq+i0+r))*Lq + j0+jj]; }
    for (int idx=tid; idx<32*56; idx+=256){
      int r = idx/56, cc = idx%56;
      float v;
      if (cc < 32) v = P[(size_t)(j0+r)*NPROJ + 512 + h*CHd + cc];
      else         v = vpg[((j0+r)*Hd+h)*24 + cc-32];
      Vt[r][cc] = v;
    }
    __syncthreads();
    if (c < 56){
      #pragma unroll
      for (int jj=0; jj<32; jj++){
        float vv = Vt[jj][c];
        #pragma unroll
        for (int q=0; q<4; q++) acc[q] += At[r4*4+q][jj]*vv;
      }
    }
    __syncthreads();
  }
  if (c < 56){
    #pragma unroll
    for (int q=0; q<4; q++){
      int i = i0 + r4*4 + q;
      if (c < 32) cat[(size_t)i*CATd + h*CHd + c] = acc[q];
      else        optg[(i*Hd+h)*24 + c-32] = acc[q];
    }
  }
}

// ------------- opair: per-query i, out[h,c] = g[c]*(sum_j (a*rs)*z - S2[h]) + b[c] -------------
__global__ __launch_bounds__(256) void k_opair(
    const float* __restrict__ abuf, const float* __restrict__ murs, const float* __restrict__ z,
    const float* __restrict__ g, const float* __restrict__ b, float* __restrict__ cat){
  __shared__ float w[Hd][Lq];
  __shared__ float wmu[Hd][Lq];
  __shared__ float red[Hd][32];
  __shared__ float S2[Hd];
  int tid = threadIdx.x;
  int i = blockIdx.x;
  for (int idx=tid; idx<Hd*Lq; idx+=256){
    int h = idx>>9, j = idx&511;
    float av = abuf[((size_t)(h*Lq+i))*Lq + j];
    float mu = murs[(i*Lq+j)*2], rs = murs[(i*Lq+j)*2+1];
    w[h][j] = av*rs;
    wmu[h][j] = av*rs*mu;
  }
  __syncthreads();
  {
    int h = tid>>5, l32 = tid&31;
    float p = 0.f;
    for (int j=l32; j<Lq; j+=32) p += wmu[h][j];
    red[h][l32] = p;
    __syncthreads();
    if (tid < Hd){
      float s = 0.f;
      #pragma unroll
      for (int q=0; q<32; q++) s += red[tid][q];
      S2[tid] = s;
    }
    __syncthreads();
  }
  int c = tid & 127, hb = tid >> 7;       // hb in {0,1}
  float acc[4] = {0.f,0.f,0.f,0.f};
  const float* zr = z + (size_t)i*Lq*CZd;
  #pragma unroll 8
  for (int j=0; j<Lq; j++){
    float zv = zr[(size_t)j*CZd + c];
    #pragma unroll
    for (int m=0; m<4; m++) acc[m] += w[hb + m*2][j]*zv;
  }
  float gv = g[c], bv = b[c];
  #pragma unroll
  for (int m=0; m<4; m++){
    int h = hb + m*2;
    cat[(size_t)i*CATd + 512 + h*CZd + c] = gv*(acc[m] - S2[h]) + bv;
  }
}

// ------------- optl = R^T(optg - t), onrm -------------
__global__ __launch_bounds__(256) void k_optl(
    const float* __restrict__ optg, const float* __restrict__ R, const float* __restrict__ t,
    float* __restrict__ cat){
  int idx = blockIdx.x*256 + threadIdx.x;   // 32768 = L*H*PV
  int l = idx >> 6, r = idx & 63;
  int h = r >> 3, p = r & 7;
  const float* og = optg + (l*Hd+h)*24 + p*3;
  float d0 = og[0]-t[l*3], d1 = og[1]-t[l*3+1], d2 = og[2]-t[l*3+2];
  const float* Rm = R + l*9;
  float o0 = Rm[0]*d0 + Rm[3]*d1 + Rm[6]*d2;
  float o1 = Rm[1]*d0 + Rm[4]*d1 + Rm[7]*d2;
  float o2 = Rm[2]*d0 + Rm[5]*d1 + Rm[8]*d2;
  float* cr = cat + (size_t)l*CATd;
  cr[256 + h*24 + p*3]   = o0;
  cr[256 + h*24 + p*3+1] = o1;
  cr[256 + h*24 + p*3+2] = o2;
  cr[448 + h*8 + p] = sqrtf(o0*o0 + o1*o1 + o2*o2 + 1e-8f);
}

// ------------- upd = sc @ wbb + bbb (N=6) -------------
__global__ __launch_bounds__(256) void k_updgemm(
    const float* __restrict__ sc, const float* __restrict__ wbb, const float* __restrict__ bbb,
    float* __restrict__ upd){
  int idx = blockIdx.x*256 + threadIdx.x;   // 3072
  int l = idx/6, o = idx%6;
  float acc = bbb[o];
  const float* row = sc + (size_t)l*CSd;
  #pragma unroll 8
  for (int k=0; k<CSd; k++) acc += row[k]*wbb[k*6+o];
  upd[l*6+o] = acc;
}

// ------------- quaternion frame update -------------
__global__ __launch_bounds__(256) void k_update(
    const float* __restrict__ upd, const float* __restrict__ mask,
    float* __restrict__ R, float* __restrict__ t){
  int l = blockIdx.x*256 + threadIdx.x;
  if (l >= Lq) return;
  const float* u = upd + l*6;
  float bq = u[0], cq = u[1], dq = u[2];
  float norm = sqrtf(1.f + bq*bq + cq*cq + dq*dq);
  float a = 1.f/norm, b_ = bq/norm, c_ = cq/norm, d_ = dq/norm;
  float dR[9];
  dR[0] = a*a + b_*b_ - c_*c_ - d_*d_; dR[1] = 2.f*(b_*c_ - a*d_); dR[2] = 2.f*(b_*d_ + a*c_);
  dR[3] = 2.f*(b_*c_ + a*d_); dR[4] = a*a - b_*b_ + c_*c_ - d_*d_; dR[5] = 2.f*(c_*d_ - a*b_);
  dR[6] = 2.f*(b_*d_ - a*c_); dR[7] = 2.f*(c_*d_ + a*b_); dR[8] = a*a - b_*b_ - c_*c_ + d_*d_;
  float mk = mask[l];
  float dt0 = u[3]*mk, dt1 = u[4]*mk, dt2 = u[5]*mk;
  float Rm[9];
  #pragma unroll
  for (int ii=0; ii<9; ii++) Rm[ii] = R[l*9+ii];
  t[l*3]   += Rm[0]*dt0 + Rm[1]*dt1 + Rm[2]*dt2;
  t[l*3+1] += Rm[3]*dt0 + Rm[4]*dt1 + Rm[5]*dt2;
  t[l*3+2] += Rm[6]*dt0 + Rm[7]*dt1 + Rm[8]*dt2;
  #pragma unroll
  for (int ii=0; ii<3; ii++)
    #pragma unroll
    for (int jj=0; jj<3; jj++)
      R[l*9 + ii*3 + jj] = Rm[ii*3]*dR[jj] + Rm[ii*3+1]*dR[3+jj] + Rm[ii*3+2]*dR[6+jj];
}

// ------------- final output write -------------
__global__ __launch_bounds__(256) void k_writeout(
    const float* __restrict__ sc, const float* __restrict__ R, const float* __restrict__ t,
    float* __restrict__ out){
  int idx = blockIdx.x*256 + threadIdx.x;
  if      (idx < 131072) out[idx] = sc[idx];
  else if (idx < 135680) out[idx] = R[idx-131072];
  else if (idx < 137216) out[idx] = t[idx-135680];
}

extern "C" void kernel_launch(void* const* d_in, const int* in_sizes, int n_in,
                              void* d_out, int out_size, void* d_ws, size_t ws_size,
                              hipStream_t stream){
  const float* s      = (const float*)d_in[0];
  const float* z      = (const float*)d_in[1];
  const float* mask   = (const float*)d_in[2];
  const float* ln_s_g = (const float*)d_in[3];
  const float* ln_s_b = (const float*)d_in[4];
  const float* ln_z_g = (const float*)d_in[5];
  const float* ln_z_b = (const float*)d_in[6];
  const float* w_init = (const float*)d_in[7];
  const float* b_init = (const float*)d_in[8];
  const float* ln_ipa_g = (const float*)d_in[9];
  const float* ln_ipa_b = (const float*)d_in[10];
  const float* ln_tr_g  = (const float*)d_in[11];
  const float* ln_tr_b  = (const float*)d_in[12];
  const float* wq = (const float*)d_in[13]; const float* bq = (const float*)d_in[14];
  const float* wk = (const float*)d_in[15]; const float* bk = (const float*)d_in[16];
  const float* wv = (const float*)d_in[17]; const float* bv = (const float*)d_in[18];
  const float* wqp = (const float*)d_in[19]; const float* bqp = (const float*)d_in[20];
  const float* wkp = (const float*)d_in[21]; const float* bkp = (const float*)d_in[22];
  const float* wvp = (const float*)d_in[23]; const float* bvp = (const float*)d_in[24];
  const float* wpb = (const float*)d_in[25];
  const float* head_w = (const float*)d_in[26];
  const float* wo = (const float*)d_in[27]; const float* bo = (const float*)d_in[28];
  const float* wt1 = (const float*)d_in[29]; const float* bt1 = (const float*)d_in[30];
  const float* wt2 = (const float*)d_in[31]; const float* bt2 = (const float*)d_in[32];
  const float* wt3 = (const float*)d_in[33]; const float* bt3 = (const float*)d_in[34];
  const float* wbb = (const float*)d_in[35]; const float* bbb = (const float*)d_in[36];

  float* W = (float*)d_ws;
  float* s0b   = W + OFF_S0;
  float* scb   = W + OFF_SC;
  float* Wcat  = W + OFF_WCAT;
  float* bcat  = W + OFF_BCAT;
  float* murs  = W + OFF_MURS;
  float* pbb   = W + OFF_PB;
  float* Pb    = W + OFF_P;
  float* qpgb  = W + OFF_QPG;
  float* kpgb  = W + OFF_KPG;
  float* vpgb  = W + OFF_VPG;
  float* qnb   = W + OFF_QN;
  float* knb   = W + OFF_KN;
  float* abuf  = W + OFF_A;
  float* catb  = W + OFF_CAT;
  float* optgb = W + OFF_OPTG;
  float* ipab  = W + OFF_IPA;
  float* tr1b  = W + OFF_TR1;
  float* tr2b  = W + OFF_TR2;
  float* tr3b  = W + OFF_TR3;
  float* Rb    = W + OFF_R;
  float* tb    = W + OFF_T;
  float* updb  = W + OFF_UPD;
  float* gammab= W + OFF_GAMMA;
  float* maskb = W + OFF_MASKB;

  // setup: Wcat(294912) + bcat(1152) + gamma(8) + maskb(512) + R/t(512)
  {
    int tot = CSd*NPROJ + NPROJ + Hd + Lq + Lq;
    k_setup<<<(tot+255)/256, 256, 0, stream>>>(wq,wk,wv,wqp,wkp,wvp,bq,bk,bv,bqp,bkp,bvp,
                                               head_w, mask, Wcat, bcat, gammab, maskb, Rb, tb);
  }
  // s0 = LN(s); sc = s0 @ w_init + b_init
  k_addln<<<Lq, 256, 0, stream>>>(s, nullptr, ln_s_g, ln_s_b, s0b);
  k_gemm<16><<<dim3(4,32), 256, 0, stream>>>(s0b, CSd, w_init, CSd, b_init, scb, CSd, CSd, 0, nullptr);
  // zn stats + pair bias
  k_lnz_pb<<<Lq*Lq/4, 256, 0, stream>>>(z, ln_z_g, ln_z_b, wpb, murs, pbb);

  for (int it=0; it<8; ++it){
    k_gemm<32><<<dim3(18,16), 256, 0, stream>>>(scb, CSd, Wcat, NPROJ, bcat, Pb, NPROJ, CSd, 0, nullptr);
    k_proj_frame<<<16, 256, 0, stream>>>(Pb, Rb, tb, qpgb, kpgb, vpgb, qnb, knb);
    k_logits<<<dim3(8,16,8), 256, 0, stream>>>(Pb, qpgb, kpgb, qnb, knb, pbb, gammab, maskb, abuf);
    k_softmax<<<Hd*Lq, 256, 0, stream>>>(abuf);
    k_av<<<dim3(32,8), 256, 0, stream>>>(abuf, Pb, vpgb, catb, optgb);
    k_opair<<<Lq, 256, 0, stream>>>(abuf, murs, z, ln_z_g, ln_z_b, catb);
    k_optl<<<128, 256, 0, stream>>>(optgb, Rb, tb, catb);
    k_gemm<16><<<dim3(4,32), 256, 0, stream>>>(catb, CATd, wo, CSd, bo, ipab, CSd, CATd, 0, nullptr);
    k_addln<<<Lq, 256, 0, stream>>>(scb, ipab, ln_ipa_g, ln_ipa_b, scb);
    k_gemm<16><<<dim3(4,32), 256, 0, stream>>>(scb, CSd, wt1, CSd, bt1, tr1b, CSd, CSd, 1, nullptr);
    k_gemm<16><<<dim3(4,32), 256, 0, stream>>>(tr1b, CSd, wt2, CSd, bt2, tr2b, CSd, CSd, 1, nullptr);
    k_gemm<16><<<dim3(4,32), 256, 0, stream>>>(tr2b, CSd, wt3, CSd, bt3, tr3b, CSd, CSd, 0, mask);
    k_addln<<<Lq, 256, 0, stream>>>(scb, tr3b, ln_tr_g, ln_tr_b, scb);
    k_updgemm<<<12, 256, 0, stream>>>(scb, wbb, bbb, updb);
    k_update<<<2, 256, 0, stream>>>(updb, mask, Rb, tb);
  }
  k_writeout<<<536, 256, 0, stream>>>(scb, Rb, tb, (float*)d_out);
}

// Round 3
// 2420.246 us; speedup vs baseline: 1.2006x; 1.2006x over previous
//
#include <hip/hip_runtime.h>
#include <hip/hip_bf16.h>
#include <math.h>

#define Lq 512
#define CSd 256
#define CZd 128
#define Hd 8
#define CHd 32
#define PQd 4
#define PVd 8
#define CATd 1536
#define NPROJ 1152

typedef __attribute__((ext_vector_type(4))) float floatx4;
typedef __attribute__((ext_vector_type(8))) short shortx8;

// ---------------- ws layout (float offsets) ----------------
#define OFF_SC      0         // 131072
#define OFF_MURS    131072    // 524288
#define OFF_PB      655360    // 2097152
#define OFF_P       2752512   // 589824
#define OFF_QPG     3342336   // 49152   (also OPTG alias: spans QPG+KPG)
#define OFF_KPG     3391488   // 49152
#define OFF_VPG     3440640   // 98304
#define OFF_QN      3538944   // 4096
#define OFF_KN      3543040   // 4096
#define OFF_A       3547136   // 2097152
#define OFF_CAT     5644288   // 786432
#define OFF_TR1     6430720   // 131072  (also S0 alias)
#define OFF_TR2     6561792   // 131072
#define OFF_TR3     6692864   // 131072  (also IPA alias)
#define OFF_R       6823936   // 4608
#define OFF_T       6828544   // 1536
#define OFF_UPD     6830080   // 3072
#define OFF_GAMMA   6833152   // 8
#define OFF_MASKB   6833160   // 512
#define OFF_BCAT    6833672   // 1152
#define OFF_WINITP  6834824   // 65536  (131072 bf16: hi/lo)
#define OFF_WT1P    6900360   // 65536
#define OFF_WT2P    6965896   // 65536
#define OFF_WT3P    7031432   // 65536
#define OFF_WOP     7096968   // 393216 (786432 bf16: hi/lo)
#define OFF_WCATP   7490184   // 294912 (589824 bf16: hi/lo)

__device__ __forceinline__ float wave_sum(float v){
  #pragma unroll
  for (int m=32; m; m>>=1) v += __shfl_xor(v, m);
  return v;
}
__device__ __forceinline__ float wave_max(float v){
  #pragma unroll
  for (int m=32; m; m>>=1) v = fmaxf(v, __shfl_xor(v, m));
  return v;
}
__device__ __forceinline__ short f2bf(float v){
  __hip_bfloat16 h = (__hip_bfloat16)v;
  return __builtin_bit_cast(short, h);
}
__device__ __forceinline__ float bf2f(short s){
  unsigned u = ((unsigned)(unsigned short)s) << 16;
  return __builtin_bit_cast(float, u);
}

// ------------- setup: bcat/gamma/maskbias/R/t -------------
__global__ __launch_bounds__(256) void k_setup(
    const float* __restrict__ bq, const float* __restrict__ bk, const float* __restrict__ bv,
    const float* __restrict__ bqp, const float* __restrict__ bkp, const float* __restrict__ bvp,
    const float* __restrict__ head_w, const float* __restrict__ mask,
    float* __restrict__ bcat, float* __restrict__ gamma,
    float* __restrict__ maskb, float* __restrict__ R, float* __restrict__ t){
  int k = blockIdx.x*256 + threadIdx.x;
  if (k < NPROJ){
    float v;
    if      (k < 256) v = bq[k];
    else if (k < 512) v = bk[k-256];
    else if (k < 768) v = bv[k-512];
    else if (k < 864) v = bqp[k-768];
    else if (k < 960) v = bkp[k-864];
    else              v = bvp[k-960];
    bcat[k] = v;
    return;
  }
  k -= NPROJ;
  if (k < Hd){ gamma[k] = log1pf(expf(head_w[k])); return; }
  k -= Hd;
  if (k < Lq){ maskb[k] = (mask[k] - 1.f)*1e9f; return; }
  k -= Lq;
  if (k < Lq){
    #pragma unroll
    for (int ii=0; ii<9; ii++) R[k*9+ii] = (ii==0||ii==4||ii==8) ? 1.f : 0.f;
    t[k*3] = 0.f; t[k*3+1] = 0.f; t[k*3+2] = 0.f;
  }
}

// ------------- pack [K,N] fp32 weight into MFMA-B hi/lo bf16 layout -------------
// tile (tk,tn) occupies 1024 bf16: [0..511]=hi, [512..1023]=lo
// pos within tile = lane*8+j, element = W[tk*32+(lane>>4)*8+j][tn*16+(lane&15)]
__global__ __launch_bounds__(256) void k_pack(
    const float* __restrict__ W, int K, int N, __hip_bfloat16* __restrict__ out){
  int idx = blockIdx.x*256 + threadIdx.x;
  if (idx >= K*N) return;
  int j = idx & 7, lane = (idx>>3) & 63, rest = idx >> 9;
  int nt = N >> 4;
  int tn = rest % nt, tk = rest / nt;
  int k = tk*32 + (lane>>4)*8 + j;
  int n = tn*16 + (lane&15);
  float v = W[(size_t)k*N + n];
  short h = f2bf(v);
  short l = f2bf(v - bf2f(h));
  size_t base = (size_t)rest*1024 + (idx & 511);
  out[base]       = __builtin_bit_cast(__hip_bfloat16, h);
  out[base + 512] = __builtin_bit_cast(__hip_bfloat16, l);
}

// ------------- pack the concatenated projection weight (virtual [256,1152]) -------------
__global__ __launch_bounds__(256) void k_pack_cat(
    const float* __restrict__ wq, const float* __restrict__ wk, const float* __restrict__ wv,
    const float* __restrict__ wqp, const float* __restrict__ wkp, const float* __restrict__ wvp,
    __hip_bfloat16* __restrict__ out){
  int idx = blockIdx.x*256 + threadIdx.x;
  if (idx >= CSd*NPROJ) return;
  int j = idx & 7, lane = (idx>>3) & 63, rest = idx >> 9;
  const int nt = NPROJ >> 4;
  int tn = rest % nt, tk = rest / nt;
  int k = tk*32 + (lane>>4)*8 + j;
  int n = tn*16 + (lane&15);
  float v;
  if      (n < 256) v = wq[k*256 + n];
  else if (n < 512) v = wk[k*256 + n-256];
  else if (n < 768) v = wv[k*256 + n-512];
  else if (n < 864) v = wqp[k*96 + n-768];
  else if (n < 960) v = wkp[k*96 + n-864];
  else              v = wvp[k*192 + n-960];
  short h = f2bf(v);
  short l = f2bf(v - bf2f(h));
  size_t base = (size_t)rest*1024 + (idx & 511);
  out[base]       = __builtin_bit_cast(__hip_bfloat16, h);
  out[base + 512] = __builtin_bit_cast(__hip_bfloat16, l);
}

// ------------- split-precision MFMA GEMM: C[512,N] = A[512,K] @ W + bias -------------
// A fp32, split hi/lo on the fly; W pre-packed hi/lo. 3 MFMAs per tile (drops lo*lo).
// block = 4 waves; wave computes 16i x 64n; grid (N/64, 8)
__global__ __launch_bounds__(256) void k_gemm_mfma(
    const float* __restrict__ A, int K,
    const __hip_bfloat16* __restrict__ Bp, int N,
    const float* __restrict__ bias,
    float* __restrict__ Cf,
    int relu, const float* __restrict__ rowscale){
  int tid = threadIdx.x;
  int wave = tid>>6, lane = tid&63;
  int i0 = blockIdx.y*64 + wave*16;
  int n0 = blockIdx.x*64;
  int quad = lane>>4, l16 = lane&15;
  floatx4 acc[4] = {};
  const int ntiles = N >> 4;
  const float* arow = A + (size_t)(i0 + l16)*K + quad*8;
  const __hip_bfloat16* bbase = Bp + ((size_t)(n0>>4))*1024 + (size_t)(lane&63)*8;
  for (int k0=0; k0<K; k0+=32){
    float4 v0 = *(const float4*)(arow + k0);
    float4 v1 = *(const float4*)(arow + k0 + 4);
    float av[8] = {v0.x,v0.y,v0.z,v0.w,v1.x,v1.y,v1.z,v1.w};
    shortx8 ahi, alo;
    #pragma unroll
    for (int j=0; j<8; j++){
      short h = f2bf(av[j]);
      ahi[j] = h;
      alo[j] = f2bf(av[j] - bf2f(h));
    }
    const __hip_bfloat16* bt = bbase + (size_t)(k0>>5)*ntiles*1024;
    #pragma unroll
    for (int s=0; s<4; s++){
      shortx8 bhi = *(const shortx8*)(bt + s*1024);
      shortx8 blo = *(const shortx8*)(bt + s*1024 + 512);
      acc[s] = __builtin_amdgcn_mfma_f32_16x16x32_bf16(ahi, bhi, acc[s], 0, 0, 0);
      acc[s] = __builtin_amdgcn_mfma_f32_16x16x32_bf16(alo, bhi, acc[s], 0, 0, 0);
      acc[s] = __builtin_amdgcn_mfma_f32_16x16x32_bf16(ahi, blo, acc[s], 0, 0, 0);
    }
  }
  #pragma unroll
  for (int s=0; s<4; s++){
    int n = n0 + s*16 + l16;
    float bs = bias ? bias[n] : 0.f;
    #pragma unroll
    for (int r=0; r<4; r++){
      int m = i0 + quad*4 + r;
      float v = acc[s][r] + bs;
      if (relu) v = fmaxf(v, 0.f);
      if (rowscale) v *= rowscale[m];
      Cf[(size_t)m*N + n] = v;
    }
  }
}

// ------------- LN over CS=256 row (optionally add y first) -------------
__global__ __launch_bounds__(256) void k_addln(
    const float* __restrict__ x, const float* __restrict__ y,
    const float* __restrict__ g, const float* __restrict__ b,
    float* __restrict__ out){
  __shared__ float red[4];
  int row = blockIdx.x, tid = threadIdx.x;
  float v = x[row*CSd + tid];
  if (y) v += y[row*CSd + tid];
  int wid = tid>>6, lane = tid&63;
  float s = wave_sum(v);
  if (lane==0) red[wid] = s;
  __syncthreads();
  float mu = (red[0]+red[1]+red[2]+red[3]) * (1.f/CSd);
  __syncthreads();
  float d = v - mu;
  float s2 = wave_sum(d*d);
  if (lane==0) red[wid] = s2;
  __syncthreads();
  float var = (red[0]+red[1]+red[2]+red[3]) * (1.f/CSd);
  float rs = rsqrtf(var + 1e-5f);
  out[row*CSd + tid] = d*rs*g[tid] + b[tid];
}

// ------------- zn stats (mu,rs) + pair_bias; tiled, FMA-based -------------
__global__ __launch_bounds__(256) void k_lnz_pb(
    const float* __restrict__ z, const float* __restrict__ g, const float* __restrict__ b,
    const float* __restrict__ wpb, float* __restrict__ murs, float* __restrict__ pb){
  __shared__ float Zt[64*129];
  __shared__ float gwt[8][132];
  __shared__ float AB[16];
  __shared__ float red[64*4*11];
  int tid = threadIdx.x;
  size_t row0 = (size_t)blockIdx.x*64;
  const float4* zsrc = (const float4*)(z + row0*CZd);
  #pragma unroll
  for (int it=0; it<8; it++){
    int idx = tid + it*256;          // 2048 float4 = 64 rows x 32
    int rr = idx>>5, qq = idx&31;
    float4 v = zsrc[idx];
    float* dst = &Zt[rr*129 + qq*4];
    dst[0]=v.x; dst[1]=v.y; dst[2]=v.z; dst[3]=v.w;
  }
  for (int idx=tid; idx<1024; idx+=256){
    int h = idx&7, c = idx>>3;
    gwt[h][c] = g[c]*wpb[c*8+h];
  }
  if (tid < 16){
    int h = tid&7; const float* src = (tid<8) ? g : b;
    float s = 0.f;
    for (int c=0; c<128; c++) s += src[c]*wpb[c*8+h];
    AB[tid] = s;
  }
  __syncthreads();
  int q = tid>>6, r = tid&63;      // wave q handles c-quarter q, lane r = row
  const float* zr = &Zt[r*129 + q*32];
  float zv[32];
  #pragma unroll
  for (int t=0; t<32; t++) zv[t] = zr[t];
  float S1=0.f, S2=0.f;
  #pragma unroll
  for (int t=0; t<32; t++){ S1 += zv[t]; S2 += zv[t]*zv[t]; }
  float* rd = &red[(r*4+q)*11];
  rd[8]=S1; rd[9]=S2;
  #pragma unroll
  for (int h=0; h<8; h++){
    const float4* gw4 = (const float4*)&gwt[h][q*32];
    float d = 0.f;
    #pragma unroll
    for (int t4=0; t4<8; t4++){
      float4 gv = gw4[t4];
      d += zv[t4*4]*gv.x + zv[t4*4+1]*gv.y + zv[t4*4+2]*gv.z + zv[t4*4+3]*gv.w;
    }
    rd[h] = d;
  }
  __syncthreads();
  if (tid < 64){
    int rr = tid;
    const float* r0 = &red[rr*44];
    float acc[10];
    #pragma unroll
    for (int v=0; v<10; v++) acc[v] = r0[v] + r0[11+v] + r0[22+v] + r0[33+v];
    float mu  = acc[8]*(1.f/128.f);
    float var = acc[9]*(1.f/128.f) - mu*mu;
    float rs  = rsqrtf(var + 1e-5f);
    size_t row = row0 + rr;
    murs[row*2] = mu; murs[row*2+1] = rs;
    int i = (int)(row>>9), j = (int)(row&511);
    #pragma unroll
    for (int h=0; h<8; h++){
      float pbv = rs*(acc[h] - mu*AB[h]) + AB[8+h];
      pb[((size_t)(h*Lq+i))*Lq + j] = pbv;
    }
  }
}

// ------------- apply frame R,t to qp/kp/vp; compute qn/kn -------------
__global__ __launch_bounds__(256) void k_proj_frame(
    const float* __restrict__ P, const float* __restrict__ R, const float* __restrict__ t,
    float* __restrict__ qpg, float* __restrict__ kpg, float* __restrict__ vpg,
    float* __restrict__ qn, float* __restrict__ kn){
  int idx = blockIdx.x*256 + threadIdx.x;   // 4096 = L*H
  int l = idx >> 3, h = idx & 7;
  float Rm[9], tv[3];
  #pragma unroll
  for (int ii=0; ii<9; ii++) Rm[ii] = R[l*9+ii];
  #pragma unroll
  for (int ii=0; ii<3; ii++) tv[ii] = t[l*3+ii];
  const float* row = P + (size_t)l*NPROJ;
  float accq = 0.f;
  #pragma unroll
  for (int p=0; p<PQd; p++){
    float x0 = row[768 + h*12 + p*3], x1 = row[768 + h*12 + p*3+1], x2 = row[768 + h*12 + p*3+2];
    float g0 = Rm[0]*x0 + Rm[1]*x1 + Rm[2]*x2 + tv[0];
    float g1 = Rm[3]*x0 + Rm[4]*x1 + Rm[5]*x2 + tv[1];
    float g2 = Rm[6]*x0 + Rm[7]*x1 + Rm[8]*x2 + tv[2];
    int o = (l*Hd + h)*12 + p*3;
    qpg[o] = g0; qpg[o+1] = g1; qpg[o+2] = g2;
    accq += g0*g0 + g1*g1 + g2*g2;
  }
  qn[l*Hd + h] = accq;
  float acck = 0.f;
  #pragma unroll
  for (int p=0; p<PQd; p++){
    float x0 = row[864 + h*12 + p*3], x1 = row[864 + h*12 + p*3+1], x2 = row[864 + h*12 + p*3+2];
    float g0 = Rm[0]*x0 + Rm[1]*x1 + Rm[2]*x2 + tv[0];
    float g1 = Rm[3]*x0 + Rm[4]*x1 + Rm[5]*x2 + tv[1];
    float g2 = Rm[6]*x0 + Rm[7]*x1 + Rm[8]*x2 + tv[2];
    int o = (l*Hd + h)*12 + p*3;
    kpg[o] = g0; kpg[o+1] = g1; kpg[o+2] = g2;
    acck += g0*g0 + g1*g1 + g2*g2;
  }
  kn[l*Hd + h] = acck;
  #pragma unroll
  for (int p=0; p<PVd; p++){
    float x0 = row[960 + h*24 + p*3], x1 = row[960 + h*24 + p*3+1], x2 = row[960 + h*24 + p*3+2];
    float g0 = Rm[0]*x0 + Rm[1]*x1 + Rm[2]*x2 + tv[0];
    float g1 = Rm[3]*x0 + Rm[4]*x1 + Rm[5]*x2 + tv[1];
    float g2 = Rm[6]*x0 + Rm[7]*x1 + Rm[8]*x2 + tv[2];
    int o = (l*Hd + h)*24 + p*3;
    vpg[o] = g0; vpg[o+1] = g1; vpg[o+2] = g2;
  }
}

// ------------- logits: per-head 32x64 tiles -------------
__global__ __launch_bounds__(256) void k_logits(
    const float* __restrict__ P, const float* __restrict__ qpg, const float* __restrict__ kpg,
    const float* __restrict__ qn, const float* __restrict__ kn, const float* __restrict__ pb,
    const float* __restrict__ gamma, const float* __restrict__ maskb, float* __restrict__ abuf){
  __shared__ float Qt[32][33];
  __shared__ float QPt[32][12];
  __shared__ float Kt[64][33];
  __shared__ float KPt[64][13];
  int tid = threadIdx.x;
  int j0 = blockIdx.x*64, i0 = blockIdx.y*32, h = blockIdx.z;
  for (int idx=tid; idx<1024; idx+=256){ int r=idx>>5, cc=idx&31; Qt[r][cc] = P[(size_t)(i0+r)*NPROJ + h*CHd + cc]; }
  for (int idx=tid; idx<384;  idx+=256){ int r=idx/12, cc=idx%12; QPt[r][cc] = qpg[((i0+r)*Hd+h)*12 + cc]; }
  for (int idx=tid; idx<2048; idx+=256){ int r=idx>>5, cc=idx&31; Kt[r][cc] = P[(size_t)(j0+r)*NPROJ + 256 + h*CHd + cc]; }
  for (int idx=tid; idx<768;  idx+=256){ int r=idx/12, cc=idx%12; KPt[r][cc] = kpg[((j0+r)*Hd+h)*12 + cc]; }
  __syncthreads();
  int j = tid & 63, ib = tid >> 6;
  float knj = kn[(j0+j)*Hd + h];
  float mb  = maskb[j0+j];
  float gam = gamma[h];
  const float wL = 0.57735026918962576f;
  const float wC = 0.23570226039551584f;
  const float iS = 0.17677669529663687f;
  #pragma unroll
  for (int r=0; r<8; r++){
    int i = ib*8 + r;
    float scal = 0.f, qk = 0.f;
    #pragma unroll
    for (int cc=0; cc<32; cc++) scal += Qt[i][cc]*Kt[j][cc];
    #pragma unroll
    for (int cc=0; cc<12; cc++) qk += QPt[i][cc]*KPt[j][cc];
    float d2 = qn[(i0+i)*Hd + h] + knj - 2.f*qk;
    float lg = wL*(scal*iS + pb[((size_t)(h*Lq + i0+i))*Lq + j0 + j] - 0.5f*wC*gam*d2) + mb;
    abuf[((size_t)(h*Lq + i0+i))*Lq + j0 + j] = lg;
  }
}

// ------------- row softmax over 512 -------------
__global__ __launch_bounds__(256) void k_softmax(float* __restrict__ abuf){
  __shared__ float red[4];
  int row = blockIdx.x, tid = threadIdx.x;
  float* base = abuf + (size_t)row*Lq;
  float v0 = base[tid], v1 = base[tid+256];
  int wid = tid>>6, lane = tid&63;
  float m = wave_max(fmaxf(v0, v1));
  if (lane==0) red[wid] = m;
  __syncthreads();
  m = fmaxf(fmaxf(red[0],red[1]), fmaxf(red[2],red[3]));
  __syncthreads();
  float e0 = __expf(v0-m), e1 = __expf(v1-m);
  float s = wave_sum(e0+e1);
  if (lane==0) red[wid] = s;
  __syncthreads();
  s = red[0]+red[1]+red[2]+red[3];
  float inv = 1.f/s;
  base[tid] = e0*inv; base[tid+256] = e1*inv;
}

// ------------- o = a@v and optg = a@vpg -------------
__global__ __launch_bounds__(256) void k_av(
    const float* __restrict__ abuf, const float* __restrict__ P, const float* __restrict__ vpg,
    float* __restrict__ cat, float* __restrict__ optg){
  __shared__ float At[16][33];
  __shared__ float Vt[33][57];
  int tid = threadIdx.x;
  int i0 = blockIdx.x*16, h = blockIdx.y;
  int c = tid & 63, r4 = tid >> 6;
  float acc[4] = {0.f,0.f,0.f,0.f};
  for (int j0=0; j0<Lq; j0+=32){
    for (int idx=tid; idx<512; idx+=256){ int r=idx>>5, jj=idx&31; At[r][jj] = abuf[((size_t)(h*Lq+i0+r))*Lq + j0+jj]; }
    for (int idx=tid; idx<32*56; idx+=256){
      int r = idx/56, cc = idx%56;
      float v;
      if (cc < 32) v = P[(size_t)(j0+r)*NPROJ + 512 + h*CHd + cc];
      else         v = vpg[((j0+r)*Hd+h)*24 + cc-32];
      Vt[r][cc] = v;
    }
    __syncthreads();
    if (c < 56){
      #pragma unroll
      for (int jj=0; jj<32; jj++){
        float vv = Vt[jj][c];
        #pragma unroll
        for (int q=0; q<4; q++) acc[q] += At[r4*4+q][jj]*vv;
      }
    }
    __syncthreads();
  }
  if (c < 56){
    #pragma unroll
    for (int q=0; q<4; q++){
      int i = i0 + r4*4 + q;
      if (c < 32) cat[(size_t)i*CATd + h*CHd + c] = acc[q];
      else        optg[(i*Hd+h)*24 + c-32] = acc[q];
    }
  }
}

// ------------- opair -------------
__global__ __launch_bounds__(256) void k_opair(
    const float* __restrict__ abuf, const float* __restrict__ murs, const float* __restrict__ z,
    const float* __restrict__ g, const float* __restrict__ b, float* __restrict__ cat){
  __shared__ float w[Hd][Lq];
  __shared__ float wmu[Hd][Lq];
  __shared__ float red[Hd][32];
  __shared__ float S2[Hd];
  int tid = threadIdx.x;
  int i = blockIdx.x;
  for (int idx=tid; idx<Hd*Lq; idx+=256){
    int h = idx>>9, j = idx&511;
    float av = abuf[((size_t)(h*Lq+i))*Lq + j];
    float mu = murs[(i*Lq+j)*2], rs = murs[(i*Lq+j)*2+1];
    w[h][j] = av*rs;
    wmu[h][j] = av*rs*mu;
  }
  __syncthreads();
  {
    int h = tid>>5, l32 = tid&31;
    float p = 0.f;
    for (int j=l32; j<Lq; j+=32) p += wmu[h][j];
    red[h][l32] = p;
    __syncthreads();
    if (tid < Hd){
      float s = 0.f;
      #pragma unroll
      for (int q=0; q<32; q++) s += red[tid][q];
      S2[tid] = s;
    }
    __syncthreads();
  }
  int c = tid & 127, hb = tid >> 7;
  float acc[4] = {0.f,0.f,0.f,0.f};
  const float* zr = z + (size_t)i*Lq*CZd;
  #pragma unroll 8
  for (int j=0; j<Lq; j++){
    float zv = zr[(size_t)j*CZd + c];
    #pragma unroll
    for (int m=0; m<4; m++) acc[m] += w[hb + m*2][j]*zv;
  }
  float gv = g[c], bv = b[c];
  #pragma unroll
  for (int m=0; m<4; m++){
    int h = hb + m*2;
    cat[(size_t)i*CATd + 512 + h*CZd + c] = gv*(acc[m] - S2[h]) + bv;
  }
}

// ------------- optl = R^T(optg - t), onrm -------------
__global__ __launch_bounds__(256) void k_optl(
    const float* __restrict__ optg, const float* __restrict__ R, const float* __restrict__ t,
    float* __restrict__ cat){
  int idx = blockIdx.x*256 + threadIdx.x;   // 32768 = L*H*PV
  int l = idx >> 6, r = idx & 63;
  int h = r >> 3, p = r & 7;
  const float* og = optg + (l*Hd+h)*24 + p*3;
  float d0 = og[0]-t[l*3], d1 = og[1]-t[l*3+1], d2 = og[2]-t[l*3+2];
  const float* Rm = R + l*9;
  float o0 = Rm[0]*d0 + Rm[3]*d1 + Rm[6]*d2;
  float o1 = Rm[1]*d0 + Rm[4]*d1 + Rm[7]*d2;
  float o2 = Rm[2]*d0 + Rm[5]*d1 + Rm[8]*d2;
  float* cr = cat + (size_t)l*CATd;
  cr[256 + h*24 + p*3]   = o0;
  cr[256 + h*24 + p*3+1] = o1;
  cr[256 + h*24 + p*3+2] = o2;
  cr[448 + h*8 + p] = sqrtf(o0*o0 + o1*o1 + o2*o2 + 1e-8f);
}

// ------------- upd = sc @ wbb + bbb (N=6) -------------
__global__ __launch_bounds__(256) void k_updgemm(
    const float* __restrict__ sc, const float* __restrict__ wbb, const float* __restrict__ bbb,
    float* __restrict__ upd){
  int idx = blockIdx.x*256 + threadIdx.x;   // 3072
  int l = idx/6, o = idx%6;
  float acc = bbb[o];
  const float* row = sc + (size_t)l*CSd;
  #pragma unroll 8
  for (int k=0; k<CSd; k++) acc += row[k]*wbb[k*6+o];
  upd[l*6+o] = acc;
}

// ------------- quaternion frame update -------------
__global__ __launch_bounds__(256) void k_update(
    const float* __restrict__ upd, const float* __restrict__ mask,
    float* __restrict__ R, float* __restrict__ t){
  int l = blockIdx.x*256 + threadIdx.x;
  if (l >= Lq) return;
  const float* u = upd + l*6;
  float bq = u[0], cq = u[1], dq = u[2];
  float norm = sqrtf(1.f + bq*bq + cq*cq + dq*dq);
  float a = 1.f/norm, b_ = bq/norm, c_ = cq/norm, d_ = dq/norm;
  float dR[9];
  dR[0] = a*a + b_*b_ - c_*c_ - d_*d_; dR[1] = 2.f*(b_*c_ - a*d_); dR[2] = 2.f*(b_*d_ + a*c_);
  dR[3] = 2.f*(b_*c_ + a*d_); dR[4] = a*a - b_*b_ + c_*c_ - d_*d_; dR[5] = 2.f*(c_*d_ - a*b_);
  dR[6] = 2.f*(b_*d_ - a*c_); dR[7] = 2.f*(c_*d_ + a*b_); dR[8] = a*a - b_*b_ - c_*c_ + d_*d_;
  float mk = mask[l];
  float dt0 = u[3]*mk, dt1 = u[4]*mk, dt2 = u[5]*mk;
  float Rm[9];
  #pragma unroll
  for (int ii=0; ii<9; ii++) Rm[ii] = R[l*9+ii];
  t[l*3]   += Rm[0]*dt0 + Rm[1]*dt1 + Rm[2]*dt2;
  t[l*3+1] += Rm[3]*dt0 + Rm[4]*dt1 + Rm[5]*dt2;
  t[l*3+2] += Rm[6]*dt0 + Rm[7]*dt1 + Rm[8]*dt2;
  #pragma unroll
  for (int ii=0; ii<3; ii++)
    #pragma unroll
    for (int jj=0; jj<3; jj++)
      R[l*9 + ii*3 + jj] = Rm[ii*3]*dR[jj] + Rm[ii*3+1]*dR[3+jj] + Rm[ii*3+2]*dR[6+jj];
}

// ------------- final output write -------------
__global__ __launch_bounds__(256) void k_writeout(
    const float* __restrict__ sc, const float* __restrict__ R, const float* __restrict__ t,
    float* __restrict__ out){
  int idx = blockIdx.x*256 + threadIdx.x;
  if      (idx < 131072) out[idx] = sc[idx];
  else if (idx < 135680) out[idx] = R[idx-131072];
  else if (idx < 137216) out[idx] = t[idx-135680];
}

extern "C" void kernel_launch(void* const* d_in, const int* in_sizes, int n_in,
                              void* d_out, int out_size, void* d_ws, size_t ws_size,
                              hipStream_t stream){
  const float* s      = (const float*)d_in[0];
  const float* z      = (const float*)d_in[1];
  const float* mask   = (const float*)d_in[2];
  const float* ln_s_g = (const float*)d_in[3];
  const float* ln_s_b = (const float*)d_in[4];
  const float* ln_z_g = (const float*)d_in[5];
  const float* ln_z_b = (const float*)d_in[6];
  const float* w_init = (const float*)d_in[7];
  const float* b_init = (const float*)d_in[8];
  const float* ln_ipa_g = (const float*)d_in[9];
  const float* ln_ipa_b = (const float*)d_in[10];
  const float* ln_tr_g  = (const float*)d_in[11];
  const float* ln_tr_b  = (const float*)d_in[12];
  const float* wq = (const float*)d_in[13]; const float* bq = (const float*)d_in[14];
  const float* wk = (const float*)d_in[15]; const float* bk = (const float*)d_in[16];
  const float* wv = (const float*)d_in[17]; const float* bv = (const float*)d_in[18];
  const float* wqp = (const float*)d_in[19]; const float* bqp = (const float*)d_in[20];
  const float* wkp = (const float*)d_in[21]; const float* bkp = (const float*)d_in[22];
  const float* wvp = (const float*)d_in[23]; const float* bvp = (const float*)d_in[24];
  const float* wpb = (const float*)d_in[25];
  const float* head_w = (const float*)d_in[26];
  const float* wo = (const float*)d_in[27]; const float* bo = (const float*)d_in[28];
  const float* wt1 = (const float*)d_in[29]; const float* bt1 = (const float*)d_in[30];
  const float* wt2 = (const float*)d_in[31]; const float* bt2 = (const float*)d_in[32];
  const float* wt3 = (const float*)d_in[33]; const float* bt3 = (const float*)d_in[34];
  const float* wbb = (const float*)d_in[35]; const float* bbb = (const float*)d_in[36];

  float* W = (float*)d_ws;
  float* scb   = W + OFF_SC;
  float* murs  = W + OFF_MURS;
  float* pbb   = W + OFF_PB;
  float* Pb    = W + OFF_P;
  float* qpgb  = W + OFF_QPG;
  float* kpgb  = W + OFF_KPG;
  float* vpgb  = W + OFF_VPG;
  float* qnb   = W + OFF_QN;
  float* knb   = W + OFF_KN;
  float* abuf  = W + OFF_A;
  float* catb  = W + OFF_CAT;
  float* tr1b  = W + OFF_TR1;
  float* tr2b  = W + OFF_TR2;
  float* tr3b  = W + OFF_TR3;
  float* s0b   = W + OFF_TR1;     // alias: dead once loop starts
  float* ipab  = W + OFF_TR3;     // alias: disjoint lifetime vs tr3
  float* optgb = W + OFF_QPG;     // alias: spans QPG+KPG, used after k_logits
  float* Rb    = W + OFF_R;
  float* tb    = W + OFF_T;
  float* updb  = W + OFF_UPD;
  float* gammab= W + OFF_GAMMA;
  float* maskb = W + OFF_MASKB;
  float* bcat  = W + OFF_BCAT;
  __hip_bfloat16* WinitP = (__hip_bfloat16*)(W + OFF_WINITP);
  __hip_bfloat16* Wt1P   = (__hip_bfloat16*)(W + OFF_WT1P);
  __hip_bfloat16* Wt2P   = (__hip_bfloat16*)(W + OFF_WT2P);
  __hip_bfloat16* Wt3P   = (__hip_bfloat16*)(W + OFF_WT3P);
  __hip_bfloat16* WoP    = (__hip_bfloat16*)(W + OFF_WOP);
  __hip_bfloat16* WcatP  = (__hip_bfloat16*)(W + OFF_WCATP);

  // setup + weight packing (hi/lo split)
  k_setup<<<9, 256, 0, stream>>>(bq,bk,bv,bqp,bkp,bvp, head_w, mask, bcat, gammab, maskb, Rb, tb);
  k_pack_cat<<<CSd*NPROJ/256, 256, 0, stream>>>(wq,wk,wv,wqp,wkp,wvp, WcatP);
  k_pack<<<256,  256, 0, stream>>>(w_init, CSd, CSd, WinitP);
  k_pack<<<1536, 256, 0, stream>>>(wo, CATd, CSd, WoP);
  k_pack<<<256,  256, 0, stream>>>(wt1, CSd, CSd, Wt1P);
  k_pack<<<256,  256, 0, stream>>>(wt2, CSd, CSd, Wt2P);
  k_pack<<<256,  256, 0, stream>>>(wt3, CSd, CSd, Wt3P);

  // s0 = LN(s); sc = s0 @ w_init + b_init
  k_addln<<<Lq, 256, 0, stream>>>(s, nullptr, ln_s_g, ln_s_b, s0b);
  k_gemm_mfma<<<dim3(4,8), 256, 0, stream>>>(s0b, CSd, WinitP, CSd, b_init, scb, 0, nullptr);
  // zn stats + pair bias
  k_lnz_pb<<<Lq*Lq/64, 256, 0, stream>>>(z, ln_z_g, ln_z_b, wpb, murs, pbb);

  for (int it=0; it<8; ++it){
    k_gemm_mfma<<<dim3(18,8), 256, 0, stream>>>(scb, CSd, WcatP, NPROJ, bcat, Pb, 0, nullptr);
    k_proj_frame<<<16, 256, 0, stream>>>(Pb, Rb, tb, qpgb, kpgb, vpgb, qnb, knb);
    k_logits<<<dim3(8,16,8), 256, 0, stream>>>(Pb, qpgb, kpgb, qnb, knb, pbb, gammab, maskb, abuf);
    k_softmax<<<Hd*Lq, 256, 0, stream>>>(abuf);
    k_av<<<dim3(32,8), 256, 0, stream>>>(abuf, Pb, vpgb, catb, optgb);
    k_opair<<<Lq, 256, 0, stream>>>(abuf, murs, z, ln_z_g, ln_z_b, catb);
    k_optl<<<128, 256, 0, stream>>>(optgb, Rb, tb, catb);
    k_gemm_mfma<<<dim3(4,8), 256, 0, stream>>>(catb, CATd, WoP, CSd, bo, ipab, 0, nullptr);
    k_addln<<<Lq, 256, 0, stream>>>(scb, ipab, ln_ipa_g, ln_ipa_b, scb);
    k_gemm_mfma<<<dim3(4,8), 256, 0, stream>>>(scb, CSd, Wt1P, CSd, bt1, tr1b, 1, nullptr);
    k_gemm_mfma<<<dim3(4,8), 256, 0, stream>>>(tr1b, CSd, Wt2P, CSd, bt2, tr2b, 1, nullptr);
    k_gemm_mfma<<<dim3(4,8), 256, 0, stream>>>(tr2b, CSd, Wt3P, CSd, bt3, tr3b, 0, mask);
    k_addln<<<Lq, 256, 0, stream>>>(scb, tr3b, ln_tr_g, ln_tr_b, scb);
    k_updgemm<<<12, 256, 0, stream>>>(scb, wbb, bbb, updb);
    k_update<<<2, 256, 0, stream>>>(updb, mask, Rb, tb);
  }
  k_writeout<<<536, 256, 0, stream>>>(scb, Rb, tb, (float*)d_out);
}

// Round 4
// 1725.301 us; speedup vs baseline: 1.6841x; 1.4028x over previous
//
#include <hip/hip_runtime.h>
#include <hip/hip_bf16.h>
#include <hip/hip_fp16.h>
#include <math.h>

#define Lq 512
#define CSd 256
#define CZd 128
#define Hd 8
#define CHd 32
#define PQd 4
#define PVd 8
#define CATd 1536
#define NPROJ 1152

typedef __attribute__((ext_vector_type(4))) float floatx4;
typedef __attribute__((ext_vector_type(8))) short shortx8;

// ---------------- ws layout (float offsets) ----------------
#define OFF_SC      0         // 131072
#define OFF_MURS    131072    // 262144 (half2 per (i,j))
#define OFF_PB      393216    // 1048576 (half)
#define OFF_P       1441792   // 589824
#define OFF_QN      2031616   // 4096
#define OFF_KN      2035712   // 4096
#define OFF_A       2039808   // 2097152
#define OFF_CAT     4136960   // 786432
#define OFF_IPA     4923392   // 131072 (also s0 alias)
#define OFF_R       5054464   // 4608
#define OFF_T       5059072   // 1536
#define OFF_GAMMA   5060608   // 8
#define OFF_MASKB   5060616   // 512
#define OFF_BCAT    5061128   // 1152
#define OFF_WINITP  5062280   // 65536
#define OFF_WT1P    5127816   // 65536
#define OFF_WT2P    5193352   // 65536
#define OFF_WT3P    5258888   // 65536
#define OFF_WOP     5324424   // 393216
#define OFF_WCATP   5717640   // 294912
#define OFF_QP      6012552   // 262144 (fp32)
#define OFF_KP      6274696   // 262144 (=524288 bf16)
#define OFF_VP      6536840   // 262144 (=524288 bf16)
// total 6798984 floats = 27.2 MB

#define WLC 0.57735026918962576f
#define WCC 0.23570226039551584f
#define ISC 0.17677669529663687f

__device__ __forceinline__ float wave_sum(float v){
  #pragma unroll
  for (int m=32; m; m>>=1) v += __shfl_xor(v, m);
  return v;
}
__device__ __forceinline__ short f2bf(float v){
  __hip_bfloat16 h = (__hip_bfloat16)v;
  return __builtin_bit_cast(short, h);
}
__device__ __forceinline__ float bf2f(short s){
  unsigned u = ((unsigned)(unsigned short)s) << 16;
  return __builtin_bit_cast(float, u);
}

// ------------- setup: bcat/gamma/maskbias/R/t -------------
__global__ __launch_bounds__(256) void k_setup(
    const float* __restrict__ bq, const float* __restrict__ bk, const float* __restrict__ bv,
    const float* __restrict__ bqp, const float* __restrict__ bkp, const float* __restrict__ bvp,
    const float* __restrict__ head_w, const float* __restrict__ mask,
    float* __restrict__ bcat, float* __restrict__ gamma,
    float* __restrict__ maskb, float* __restrict__ R, float* __restrict__ t){
  int k = blockIdx.x*256 + threadIdx.x;
  if (k < NPROJ){
    float v;
    if      (k < 256) v = bq[k];
    else if (k < 512) v = bk[k-256];
    else if (k < 768) v = bv[k-512];
    else if (k < 864) v = bqp[k-768];
    else if (k < 960) v = bkp[k-864];
    else              v = bvp[k-960];
    bcat[k] = v;
    return;
  }
  k -= NPROJ;
  if (k < Hd){ gamma[k] = log1pf(expf(head_w[k])); return; }
  k -= Hd;
  if (k < Lq){ maskb[k] = (mask[k] - 1.f)*1e9f; return; }
  k -= Lq;
  if (k < Lq){
    #pragma unroll
    for (int ii=0; ii<9; ii++) R[k*9+ii] = (ii==0||ii==4||ii==8) ? 1.f : 0.f;
    t[k*3] = 0.f; t[k*3+1] = 0.f; t[k*3+2] = 0.f;
  }
}

// ------------- pack [K,N] fp32 weight into MFMA-B hi/lo bf16 layout -------------
__global__ __launch_bounds__(256) void k_pack(
    const float* __restrict__ W, int K, int N, __hip_bfloat16* __restrict__ out){
  int idx = blockIdx.x*256 + threadIdx.x;
  if (idx >= K*N) return;
  int j = idx & 7, lane = (idx>>3) & 63, rest = idx >> 9;
  int nt = N >> 4;
  int tn = rest % nt, tk = rest / nt;
  int k = tk*32 + (lane>>4)*8 + j;
  int n = tn*16 + (lane&15);
  float v = W[(size_t)k*N + n];
  short h = f2bf(v);
  short l = f2bf(v - bf2f(h));
  size_t base = (size_t)rest*1024 + (idx & 511);
  out[base]       = __builtin_bit_cast(__hip_bfloat16, h);
  out[base + 512] = __builtin_bit_cast(__hip_bfloat16, l);
}

// ------------- pack the concatenated projection weight (virtual [256,1152]) -------------
__global__ __launch_bounds__(256) void k_pack_cat(
    const float* __restrict__ wq, const float* __restrict__ wk, const float* __restrict__ wv,
    const float* __restrict__ wqp, const float* __restrict__ wkp, const float* __restrict__ wvp,
    __hip_bfloat16* __restrict__ out){
  int idx = blockIdx.x*256 + threadIdx.x;
  if (idx >= CSd*NPROJ) return;
  int j = idx & 7, lane = (idx>>3) & 63, rest = idx >> 9;
  const int nt = NPROJ >> 4;
  int tn = rest % nt, tk = rest / nt;
  int k = tk*32 + (lane>>4)*8 + j;
  int n = tn*16 + (lane&15);
  float v;
  if      (n < 256) v = wq[k*256 + n];
  else if (n < 512) v = wk[k*256 + n-256];
  else if (n < 768) v = wv[k*256 + n-512];
  else if (n < 864) v = wqp[k*96 + n-768];
  else if (n < 960) v = wkp[k*96 + n-864];
  else              v = wvp[k*192 + n-960];
  short h = f2bf(v);
  short l = f2bf(v - bf2f(h));
  size_t base = (size_t)rest*1024 + (idx & 511);
  out[base]       = __builtin_bit_cast(__hip_bfloat16, h);
  out[base + 512] = __builtin_bit_cast(__hip_bfloat16, l);
}

// ------------- split-precision MFMA GEMM: C[512,N] = A[512,K] @ W + bias -------------
__global__ __launch_bounds__(256) void k_gemm_mfma(
    const float* __restrict__ A, int K,
    const __hip_bfloat16* __restrict__ Bp, int N,
    const float* __restrict__ bias,
    float* __restrict__ Cf,
    int relu, const float* __restrict__ rowscale){
  int tid = threadIdx.x;
  int wave = tid>>6, lane = tid&63;
  int i0 = blockIdx.y*64 + wave*16;
  int n0 = blockIdx.x*64;
  int quad = lane>>4, l16 = lane&15;
  floatx4 acc[4] = {};
  const int ntiles = N >> 4;
  const float* arow = A + (size_t)(i0 + l16)*K + quad*8;
  const __hip_bfloat16* bbase = Bp + ((size_t)(n0>>4))*1024 + (size_t)(lane&63)*8;
  for (int k0=0; k0<K; k0+=32){
    float4 v0 = *(const float4*)(arow + k0);
    float4 v1 = *(const float4*)(arow + k0 + 4);
    float av[8] = {v0.x,v0.y,v0.z,v0.w,v1.x,v1.y,v1.z,v1.w};
    shortx8 ahi, alo;
    #pragma unroll
    for (int j=0; j<8; j++){
      short h = f2bf(av[j]);
      ahi[j] = h;
      alo[j] = f2bf(av[j] - bf2f(h));
    }
    const __hip_bfloat16* bt = bbase + (size_t)(k0>>5)*ntiles*1024;
    #pragma unroll
    for (int s=0; s<4; s++){
      shortx8 bhi = *(const shortx8*)(bt + s*1024);
      shortx8 blo = *(const shortx8*)(bt + s*1024 + 512);
      acc[s] = __builtin_amdgcn_mfma_f32_16x16x32_bf16(ahi, bhi, acc[s], 0, 0, 0);
      acc[s] = __builtin_amdgcn_mfma_f32_16x16x32_bf16(alo, bhi, acc[s], 0, 0, 0);
      acc[s] = __builtin_amdgcn_mfma_f32_16x16x32_bf16(ahi, blo, acc[s], 0, 0, 0);
    }
  }
  #pragma unroll
  for (int s=0; s<4; s++){
    int n = n0 + s*16 + l16;
    float bs = bias ? bias[n] : 0.f;
    #pragma unroll
    for (int r=0; r<4; r++){
      int m = i0 + quad*4 + r;
      float v = acc[s][r] + bs;
      if (relu) v = fmaxf(v, 0.f);
      if (rowscale) v *= rowscale[m];
      Cf[(size_t)m*N + n] = v;
    }
  }
}

// ------------- LN over CS=256 row -------------
__global__ __launch_bounds__(256) void k_addln(
    const float* __restrict__ x, const float* __restrict__ y,
    const float* __restrict__ g, const float* __restrict__ b,
    float* __restrict__ out){
  __shared__ float red[4];
  int row = blockIdx.x, tid = threadIdx.x;
  float v = x[row*CSd + tid];
  if (y) v += y[row*CSd + tid];
  int wid = tid>>6, lane = tid&63;
  float s = wave_sum(v);
  if (lane==0) red[wid] = s;
  __syncthreads();
  float mu = (red[0]+red[1]+red[2]+red[3]) * (1.f/CSd);
  __syncthreads();
  float d = v - mu;
  float s2 = wave_sum(d*d);
  if (lane==0) red[wid] = s2;
  __syncthreads();
  float var = (red[0]+red[1]+red[2]+red[3]) * (1.f/CSd);
  float rs = rsqrtf(var + 1e-5f);
  out[row*CSd + tid] = d*rs*g[tid] + b[tid];
}

// ------------- zn stats (mu,rs as half2) + pair_bias (half) -------------
__global__ __launch_bounds__(256) void k_lnz_pb(
    const float* __restrict__ z, const float* __restrict__ g, const float* __restrict__ b,
    const float* __restrict__ wpb, __half2* __restrict__ murs, __half* __restrict__ pb){
  __shared__ float Zt[64*129];
  __shared__ float gwt[8][132];
  __shared__ float AB[16];
  __shared__ float red[64*4*11];
  int tid = threadIdx.x;
  size_t row0 = (size_t)blockIdx.x*64;
  const float4* zsrc = (const float4*)(z + row0*CZd);
  #pragma unroll
  for (int it=0; it<8; it++){
    int idx = tid + it*256;
    int rr = idx>>5, qq = idx&31;
    float4 v = zsrc[idx];
    float* dst = &Zt[rr*129 + qq*4];
    dst[0]=v.x; dst[1]=v.y; dst[2]=v.z; dst[3]=v.w;
  }
  for (int idx=tid; idx<1024; idx+=256){
    int h = idx&7, c = idx>>3;
    gwt[h][c] = g[c]*wpb[c*8+h];
  }
  if (tid < 16){
    int h = tid&7; const float* src = (tid<8) ? g : b;
    float s = 0.f;
    for (int c=0; c<128; c++) s += src[c]*wpb[c*8+h];
    AB[tid] = s;
  }
  __syncthreads();
  int q = tid>>6, r = tid&63;
  const float* zr = &Zt[r*129 + q*32];
  float zv[32];
  #pragma unroll
  for (int t=0; t<32; t++) zv[t] = zr[t];
  float S1=0.f, S2=0.f;
  #pragma unroll
  for (int t=0; t<32; t++){ S1 += zv[t]; S2 += zv[t]*zv[t]; }
  float* rd = &red[(r*4+q)*11];
  rd[8]=S1; rd[9]=S2;
  #pragma unroll
  for (int h=0; h<8; h++){
    const float4* gw4 = (const float4*)&gwt[h][q*32];
    float d = 0.f;
    #pragma unroll
    for (int t4=0; t4<8; t4++){
      float4 gv = gw4[t4];
      d += zv[t4*4]*gv.x + zv[t4*4+1]*gv.y + zv[t4*4+2]*gv.z + zv[t4*4+3]*gv.w;
    }
    rd[h] = d;
  }
  __syncthreads();
  if (tid < 64){
    int rr = tid;
    const float* r0 = &red[rr*44];
    float acc[10];
    #pragma unroll
    for (int v=0; v<10; v++) acc[v] = r0[v] + r0[11+v] + r0[22+v] + r0[33+v];
    float mu  = acc[8]*(1.f/128.f);
    float var = acc[9]*(1.f/128.f) - mu*mu;
    float rs  = rsqrtf(var + 1e-5f);
    size_t row = row0 + rr;
    murs[row] = __floats2half2_rn(mu, rs);
    int i = (int)(row>>9), j = (int)(row&511);
    #pragma unroll
    for (int h=0; h<8; h++){
      float pbv = rs*(acc[h] - mu*AB[h]) + AB[8+h];
      pb[((size_t)(h*Lq+i))*Lq + j] = __float2half(pbv);
    }
  }
}

// ------------- pack Q'/K'/V' in MFMA layouts, compute qn/kn -------------
__global__ __launch_bounds__(256) void k_packqkv(
    const float* __restrict__ P, const float* __restrict__ R, const float* __restrict__ t,
    const float* __restrict__ gamma,
    float* __restrict__ Qp, __hip_bfloat16* __restrict__ Kp, __hip_bfloat16* __restrict__ Vp,
    float* __restrict__ qn, float* __restrict__ kn){
  int idx = blockIdx.x*256 + threadIdx.x;   // 3*262144
  int region = idx >> 18;
  int rem = idx & 262143;
  int h = rem >> 15;
  int r2 = rem & 32767;
  if (region == 0){
    int j = r2 >> 6, f = r2 & 63;
    float val = 0.f;
    if (f < 32) val = P[(size_t)j*NPROJ + 256 + h*CHd + f];
    else if (f < 44){
      int p = (f-32)/3, ax = (f-32)%3;
      const float* kp = P + (size_t)j*NPROJ + 864 + h*12 + p*3;
      const float* Rr = R + j*9 + ax*3;
      val = Rr[0]*kp[0] + Rr[1]*kp[1] + Rr[2]*kp[2] + t[j*3+ax];
    }
    short hi = f2bf(val), lo = f2bf(val - bf2f(hi));
    int kc = f>>5, jt = j>>4, l16 = j&15, fl = f&31, quad = fl>>3, jj = f&7;
    size_t base = (size_t)((h*2+kc)*32 + jt)*1024 + (quad*16+l16)*8 + jj;
    Kp[base] = __builtin_bit_cast(__hip_bfloat16, hi);
    Kp[base+512] = __builtin_bit_cast(__hip_bfloat16, lo);
    if (f == 0){
      const float* Rm = R + j*9; const float* tv = t + j*3;
      float acc = 0.f;
      #pragma unroll
      for (int p=0; p<PQd; p++){
        const float* kp = P + (size_t)j*NPROJ + 864 + h*12 + p*3;
        #pragma unroll
        for (int ax=0; ax<3; ax++){
          float g = Rm[ax*3]*kp[0] + Rm[ax*3+1]*kp[1] + Rm[ax*3+2]*kp[2] + tv[ax];
          acc += g*g;
        }
      }
      kn[j*Hd + h] = acc;
    }
  } else if (region == 1){
    int j = r2 >> 6, n = r2 & 63;
    float val = 0.f;
    if (n < 32) val = P[(size_t)j*NPROJ + 512 + h*CHd + n];
    else if (n < 56){
      int p = (n-32)/3, ax = (n-32)%3;
      const float* vp = P + (size_t)j*NPROJ + 960 + h*24 + p*3;
      const float* Rr = R + j*9 + ax*3;
      val = Rr[0]*vp[0] + Rr[1]*vp[1] + Rr[2]*vp[2] + t[j*3+ax];
    }
    short hi = f2bf(val), lo = f2bf(val - bf2f(hi));
    int kc2 = j>>5, w = n>>4, l16 = n&15, jl = j&31, quad = jl>>3, jj = j&7;
    size_t base = (size_t)((h*16+kc2)*4 + w)*1024 + (quad*16+l16)*8 + jj;
    Vp[base] = __builtin_bit_cast(__hip_bfloat16, hi);
    Vp[base+512] = __builtin_bit_cast(__hip_bfloat16, lo);
  } else {
    int i = r2 >> 6, f = r2 & 63;
    float val = 0.f;
    if (f < 32) val = P[(size_t)i*NPROJ + h*CHd + f] * (WLC*ISC);
    else if (f < 44){
      int p = (f-32)/3, ax = (f-32)%3;
      const float* qp = P + (size_t)i*NPROJ + 768 + h*12 + p*3;
      const float* Rr = R + i*9 + ax*3;
      float g = Rr[0]*qp[0] + Rr[1]*qp[1] + Rr[2]*qp[2] + t[i*3+ax];
      val = g * (WLC*WCC*gamma[h]);
    }
    Qp[((size_t)h*512 + i)*64 + f] = val;
    if (f == 0){
      const float* Rm = R + i*9; const float* tv = t + i*3;
      float acc = 0.f;
      #pragma unroll
      for (int p=0; p<PQd; p++){
        const float* qp = P + (size_t)i*NPROJ + 768 + h*12 + p*3;
        #pragma unroll
        for (int ax=0; ax<3; ax++){
          float g = Rm[ax*3]*qp[0] + Rm[ax*3+1]*qp[1] + Rm[ax*3+2]*qp[2] + tv[ax];
          acc += g*g;
        }
      }
      qn[i*Hd + h] = acc;
    }
  }
}

// ------------- fused attention: QK^T + softmax + A@V' + optl/onrm -------------
__global__ __launch_bounds__(256) void k_attn(
    const float* __restrict__ Qp, const __hip_bfloat16* __restrict__ Kp,
    const __hip_bfloat16* __restrict__ Vp,
    const float* __restrict__ qn, const float* __restrict__ kn,
    const __half* __restrict__ pb, const float* __restrict__ maskb,
    const float* __restrict__ gamma,
    const float* __restrict__ R, const float* __restrict__ t,
    float* __restrict__ abuf, float* __restrict__ cat){
  __shared__ float At[16][516];
  __shared__ float Ot[16][36];
  __shared__ float red1[16][16];
  __shared__ float red2[16][16];
  __shared__ float invL[16];
  __shared__ float qnL[16];
  int tid = threadIdx.x;
  int i0 = blockIdx.x*16, h = blockIdx.y;
  int wave = tid>>6, lane = tid&63, quad = lane>>4, l16 = lane&15;
  float gam = gamma[h];
  float coef = 0.5f*WLC*WCC*gam;
  if (tid < 16) qnL[tid] = qn[(i0+tid)*Hd + h];
  __syncthreads();
  // ---- QK phase ----
  const float* qrow = Qp + ((size_t)h*512 + i0 + l16)*64 + quad*8;
  for (int it=0; it<8; it++){
    int jt = it*4 + wave;
    floatx4 acc = {};
    #pragma unroll
    for (int kc=0; kc<2; kc++){
      float4 v0 = *(const float4*)(qrow + kc*32);
      float4 v1 = *(const float4*)(qrow + kc*32 + 4);
      float av[8] = {v0.x,v0.y,v0.z,v0.w,v1.x,v1.y,v1.z,v1.w};
      shortx8 ahi, alo;
      #pragma unroll
      for (int j=0; j<8; j++){
        short hh = f2bf(av[j]);
        ahi[j] = hh; alo[j] = f2bf(av[j] - bf2f(hh));
      }
      const __hip_bfloat16* bt = Kp + (size_t)((h*2+kc)*32 + jt)*1024 + lane*8;
      shortx8 bhi = *(const shortx8*)bt;
      shortx8 blo = *(const shortx8*)(bt + 512);
      acc = __builtin_amdgcn_mfma_f32_16x16x32_bf16(ahi, bhi, acc, 0, 0, 0);
      acc = __builtin_amdgcn_mfma_f32_16x16x32_bf16(alo, bhi, acc, 0, 0, 0);
      acc = __builtin_amdgcn_mfma_f32_16x16x32_bf16(ahi, blo, acc, 0, 0, 0);
    }
    int j = jt*16 + l16;
    float knj = kn[j*Hd + h];
    float mbj = maskb[j];
    #pragma unroll
    for (int r=0; r<4; r++){
      int i = quad*4 + r;
      float pbv = __half2float(pb[((size_t)(h*Lq) + i0 + i)*Lq + j]);
      At[i][j] = acc[r] + WLC*pbv + mbj - coef*(qnL[i] + knj);
    }
  }
  __syncthreads();
  // ---- softmax (strided cols to avoid bank conflicts) ----
  int srow = tid>>4, sseg = tid&15;
  {
    float m = -1e30f;
    #pragma unroll 8
    for (int k2=0; k2<32; k2++) m = fmaxf(m, At[srow][sseg + k2*16]);
    red1[srow][sseg] = m;
  }
  __syncthreads();
  float mrow = red1[srow][0];
  #pragma unroll
  for (int c=1;c<16;c++) mrow = fmaxf(mrow, red1[srow][c]);
  {
    float ssum = 0.f;
    #pragma unroll 8
    for (int k2=0; k2<32; k2++){
      int cc = sseg + k2*16;
      float e = __expf(At[srow][cc]-mrow);
      At[srow][cc] = e; ssum += e;
    }
    red2[srow][sseg] = ssum;
  }
  __syncthreads();
  if (tid < 16){
    float s=0.f;
    #pragma unroll
    for (int c=0;c<16;c++) s += red2[tid][c];
    invL[tid] = 1.f/s;
  }
  __syncthreads();
  for (int idx2=tid; idx2<8192; idx2+=256){
    int rr = idx2>>9, cc = idx2&511;
    float v = At[rr][cc]*invL[rr];
    At[rr][cc] = v;
    abuf[((size_t)(h*Lq)+i0+rr)*Lq + cc] = v;
  }
  __syncthreads();
  // ---- AV phase ----
  floatx4 acc2 = {};
  for (int kc2=0; kc2<16; kc2++){
    const float* ar = &At[l16][kc2*32 + quad*8];
    float4 v0 = *(const float4*)ar;
    float4 v1 = *(const float4*)(ar+4);
    float av[8] = {v0.x,v0.y,v0.z,v0.w,v1.x,v1.y,v1.z,v1.w};
    shortx8 ahi, alo;
    #pragma unroll
    for (int j=0; j<8; j++){
      short hh = f2bf(av[j]);
      ahi[j] = hh; alo[j] = f2bf(av[j] - bf2f(hh));
    }
    const __hip_bfloat16* bt = Vp + (size_t)((h*16+kc2)*4 + wave)*1024 + lane*8;
    shortx8 bhi = *(const shortx8*)bt;
    shortx8 blo = *(const shortx8*)(bt + 512);
    acc2 = __builtin_amdgcn_mfma_f32_16x16x32_bf16(ahi, bhi, acc2, 0, 0, 0);
    acc2 = __builtin_amdgcn_mfma_f32_16x16x32_bf16(alo, bhi, acc2, 0, 0, 0);
    acc2 = __builtin_amdgcn_mfma_f32_16x16x32_bf16(ahi, blo, acc2, 0, 0, 0);
  }
  {
    int n = wave*16 + l16;
    #pragma unroll
    for (int r=0;r<4;r++){
      int i = quad*4+r;
      if (n < 32) cat[(size_t)(i0+i)*CATd + h*CHd + n] = acc2[r];
      else        Ot[i][n-32] = acc2[r];
    }
  }
  __syncthreads();
  if (tid < 128){
    int i = tid>>3, p = tid&7, gi = i0+i;
    float o0 = Ot[i][p*3], o1 = Ot[i][p*3+1], o2 = Ot[i][p*3+2];
    float d0 = o0 - t[gi*3], d1 = o1 - t[gi*3+1], d2 = o2 - t[gi*3+2];
    const float* Rm = R + gi*9;
    float l0 = Rm[0]*d0 + Rm[3]*d1 + Rm[6]*d2;
    float l1 = Rm[1]*d0 + Rm[4]*d1 + Rm[7]*d2;
    float l2 = Rm[2]*d0 + Rm[5]*d1 + Rm[8]*d2;
    float* cr = cat + (size_t)gi*CATd;
    cr[256 + h*24 + p*3]   = l0;
    cr[256 + h*24 + p*3+1] = l1;
    cr[256 + h*24 + p*3+2] = l2;
    cr[448 + h*8 + p] = sqrtf(l0*l0 + l1*l1 + l2*l2 + 1e-8f);
  }
}

// ------------- opair -------------
__global__ __launch_bounds__(256) void k_opair(
    const float* __restrict__ abuf, const __half2* __restrict__ murs, const float* __restrict__ z,
    const float* __restrict__ g, const float* __restrict__ b, float* __restrict__ cat){
  __shared__ float w[Hd][Lq];
  __shared__ float wmu[Hd][Lq];
  __shared__ float red[Hd][32];
  __shared__ float S2[Hd];
  int tid = threadIdx.x;
  int i = blockIdx.x;
  for (int idx=tid; idx<Hd*Lq; idx+=256){
    int h = idx>>9, j = idx&511;
    float av = abuf[((size_t)(h*Lq+i))*Lq + j];
    __half2 mr = murs[i*Lq + j];
    float mu = __low2float(mr), rs = __high2float(mr);
    w[h][j] = av*rs;
    wmu[h][j] = av*rs*mu;
  }
  __syncthreads();
  {
    int h = tid>>5, l32 = tid&31;
    float p = 0.f;
    for (int j=l32; j<Lq; j+=32) p += wmu[h][j];
    red[h][l32] = p;
    __syncthreads();
    if (tid < Hd){
      float s = 0.f;
      #pragma unroll
      for (int q=0; q<32; q++) s += red[tid][q];
      S2[tid] = s;
    }
    __syncthreads();
  }
  int c = tid & 127, hb = tid >> 7;
  float acc[4] = {0.f,0.f,0.f,0.f};
  const float* zr = z + (size_t)i*Lq*CZd;
  #pragma unroll 8
  for (int j=0; j<Lq; j++){
    float zv = zr[(size_t)j*CZd + c];
    #pragma unroll
    for (int m=0; m<4; m++) acc[m] += w[hb + m*2][j]*zv;
  }
  float gv = g[c], bv = b[c];
  #pragma unroll
  for (int m=0; m<4; m++){
    int h = hb + m*2;
    cat[(size_t)i*CATd + 512 + h*CZd + c] = gv*(acc[m] - S2[h]) + bv;
  }
}

// ------------- mega transition: LN + 3 GEMMs + LN + upd + frame update -------------
__device__ __forceinline__ void gemm_stage(
    const float (*X)[260], float (*Y)[260],
    const __hip_bfloat16* __restrict__ Wp, const float* __restrict__ bias,
    bool relu, int tid){
  int wave = tid>>6, lane = tid&63, quad = lane>>4, l16 = lane&15;
  floatx4 acc[4] = {};
  for (int kc=0; kc<8; kc++){
    const float* xr = &X[l16][kc*32 + quad*8];
    float4 v0 = *(const float4*)xr;
    float4 v1 = *(const float4*)(xr+4);
    float av[8] = {v0.x,v0.y,v0.z,v0.w,v1.x,v1.y,v1.z,v1.w};
    shortx8 ahi, alo;
    #pragma unroll
    for (int j=0; j<8; j++){
      short hh = f2bf(av[j]);
      ahi[j] = hh; alo[j] = f2bf(av[j] - bf2f(hh));
    }
    #pragma unroll
    for (int ns=0; ns<4; ns++){
      const __hip_bfloat16* bt = Wp + (size_t)(kc*16 + wave*4 + ns)*1024 + lane*8;
      shortx8 bhi = *(const shortx8*)bt;
      shortx8 blo = *(const shortx8*)(bt + 512);
      acc[ns] = __builtin_amdgcn_mfma_f32_16x16x32_bf16(ahi, bhi, acc[ns], 0, 0, 0);
      acc[ns] = __builtin_amdgcn_mfma_f32_16x16x32_bf16(alo, bhi, acc[ns], 0, 0, 0);
      acc[ns] = __builtin_amdgcn_mfma_f32_16x16x32_bf16(ahi, blo, acc[ns], 0, 0, 0);
    }
  }
  #pragma unroll
  for (int ns=0; ns<4; ns++){
    int n = wave*64 + ns*16 + l16;
    float bs = bias[n];
    #pragma unroll
    for (int r=0;r<4;r++){
      float v = acc[ns][r] + bs;
      if (relu) v = fmaxf(v, 0.f);
      Y[quad*4+r][n] = v;
    }
  }
}

__global__ __launch_bounds__(256) void k_mega(
    float* __restrict__ scb, const float* __restrict__ ipab,
    const float* __restrict__ gi_, const float* __restrict__ bi_,
    const __hip_bfloat16* __restrict__ W1, const float* __restrict__ c1,
    const __hip_bfloat16* __restrict__ W2, const float* __restrict__ c2,
    const __hip_bfloat16* __restrict__ W3, const float* __restrict__ c3,
    const float* __restrict__ gt_, const float* __restrict__ bt_,
    const float* __restrict__ mask,
    const float* __restrict__ wbb, const float* __restrict__ bbb,
    float* __restrict__ R, float* __restrict__ t){
  __shared__ float As[16][260], Bs[16][260], Cs[16][260];
  __shared__ float rA[16][17], rB[16][17];
  __shared__ float mv[16][2];
  __shared__ float u6[16][6];
  int tid = threadIdx.x;
  int i0 = blockIdx.x*16;
  int r = tid>>4, c0 = (tid&15)*16;
  float v[16];
  // stage 0: LN(sc + ipa)
  {
    const float* sr = scb  + (size_t)(i0+r)*CSd + c0;
    const float* ir = ipab + (size_t)(i0+r)*CSd + c0;
    float s1=0.f, s2=0.f;
    #pragma unroll
    for (int k2=0;k2<16;k2++){ float x = sr[k2]+ir[k2]; v[k2]=x; s1+=x; s2+=x*x; }
    rA[r][tid&15]=s1; rB[r][tid&15]=s2;
  }
  __syncthreads();
  if (tid<16){
    float s1=0.f,s2=0.f;
    #pragma unroll
    for (int c=0;c<16;c++){ s1+=rA[tid][c]; s2+=rB[tid][c]; }
    float mu = s1*(1.f/CSd), var = s2*(1.f/CSd) - mu*mu;
    mv[tid][0]=mu; mv[tid][1]=rsqrtf(var+1e-5f);
  }
  __syncthreads();
  {
    float mu=mv[r][0], rs=mv[r][1];
    #pragma unroll
    for (int k2=0;k2<16;k2++) As[r][c0+k2] = (v[k2]-mu)*rs*gi_[c0+k2] + bi_[c0+k2];
  }
  __syncthreads();
  gemm_stage(As, Bs, W1, c1, true, tid);
  __syncthreads();
  gemm_stage(Bs, Cs, W2, c2, true, tid);
  __syncthreads();
  gemm_stage(Cs, Bs, W3, c3, false, tid);
  __syncthreads();
  // stage 4: LN(sc_new + tr3*mask)
  {
    float mk = mask[i0+r];
    float s1=0.f, s2=0.f;
    #pragma unroll
    for (int k2=0;k2<16;k2++){ float x = As[r][c0+k2] + Bs[r][c0+k2]*mk; v[k2]=x; s1+=x; s2+=x*x; }
    rA[r][tid&15]=s1; rB[r][tid&15]=s2;
  }
  __syncthreads();
  if (tid<16){
    float s1=0.f,s2=0.f;
    #pragma unroll
    for (int c=0;c<16;c++){ s1+=rA[tid][c]; s2+=rB[tid][c]; }
    float mu = s1*(1.f/CSd), var = s2*(1.f/CSd) - mu*mu;
    mv[tid][0]=mu; mv[tid][1]=rsqrtf(var+1e-5f);
  }
  __syncthreads();
  {
    float mu=mv[r][0], rs=mv[r][1];
    float* out = scb + (size_t)(i0+r)*CSd + c0;
    #pragma unroll
    for (int k2=0;k2<16;k2++){
      float o = (v[k2]-mu)*rs*gt_[c0+k2] + bt_[c0+k2];
      As[r][c0+k2] = o;
      out[k2] = o;
    }
  }
  __syncthreads();
  // stage 5: upd + quat update
  if (tid < 96){
    int rr = tid/6, o = tid%6;
    float acc = bbb[o];
    for (int k2=0;k2<CSd;k2++) acc += As[rr][k2]*wbb[k2*6+o];
    u6[rr][o] = acc;
  }
  __syncthreads();
  if (tid < 16){
    int gidx = i0 + tid;
    float bq = u6[tid][0], cq = u6[tid][1], dq = u6[tid][2];
    float norm = sqrtf(1.f + bq*bq + cq*cq + dq*dq);
    float a = 1.f/norm, b_ = bq/norm, c_ = cq/norm, d_ = dq/norm;
    float dR[9];
    dR[0] = a*a + b_*b_ - c_*c_ - d_*d_; dR[1] = 2.f*(b_*c_ - a*d_); dR[2] = 2.f*(b_*d_ + a*c_);
    dR[3] = 2.f*(b_*c_ + a*d_); dR[4] = a*a - b_*b_ + c_*c_ - d_*d_; dR[5] = 2.f*(c_*d_ - a*b_);
    dR[6] = 2.f*(b_*d_ - a*c_); dR[7] = 2.f*(c_*d_ + a*b_); dR[8] = a*a - b_*b_ - c_*c_ + d_*d_;
    float mk = mask[gidx];
    float dt0 = u6[tid][3]*mk, dt1 = u6[tid][4]*mk, dt2 = u6[tid][5]*mk;
    float Rm[9];
    #pragma unroll
    for (int ii=0; ii<9; ii++) Rm[ii] = R[gidx*9+ii];
    t[gidx*3]   += Rm[0]*dt0 + Rm[1]*dt1 + Rm[2]*dt2;
    t[gidx*3+1] += Rm[3]*dt0 + Rm[4]*dt1 + Rm[5]*dt2;
    t[gidx*3+2] += Rm[6]*dt0 + Rm[7]*dt1 + Rm[8]*dt2;
    #pragma unroll
    for (int ii=0; ii<3; ii++)
      #pragma unroll
      for (int jj=0; jj<3; jj++)
        R[gidx*9 + ii*3 + jj] = Rm[ii*3]*dR[jj] + Rm[ii*3+1]*dR[3+jj] + Rm[ii*3+2]*dR[6+jj];
  }
}

// ------------- final output write -------------
__global__ __launch_bounds__(256) void k_writeout(
    const float* __restrict__ sc, const float* __restrict__ R, const float* __restrict__ t,
    float* __restrict__ out){
  int idx = blockIdx.x*256 + threadIdx.x;
  if      (idx < 131072) out[idx] = sc[idx];
  else if (idx < 135680) out[idx] = R[idx-131072];
  else if (idx < 137216) out[idx] = t[idx-135680];
}

extern "C" void kernel_launch(void* const* d_in, const int* in_sizes, int n_in,
                              void* d_out, int out_size, void* d_ws, size_t ws_size,
                              hipStream_t stream){
  const float* s      = (const float*)d_in[0];
  const float* z      = (const float*)d_in[1];
  const float* mask   = (const float*)d_in[2];
  const float* ln_s_g = (const float*)d_in[3];
  const float* ln_s_b = (const float*)d_in[4];
  const float* ln_z_g = (const float*)d_in[5];
  const float* ln_z_b = (const float*)d_in[6];
  const float* w_init = (const float*)d_in[7];
  const float* b_init = (const float*)d_in[8];
  const float* ln_ipa_g = (const float*)d_in[9];
  const float* ln_ipa_b = (const float*)d_in[10];
  const float* ln_tr_g  = (const float*)d_in[11];
  const float* ln_tr_b  = (const float*)d_in[12];
  const float* wq = (const float*)d_in[13]; const float* bq = (const float*)d_in[14];
  const float* wk = (const float*)d_in[15]; const float* bk = (const float*)d_in[16];
  const float* wv = (const float*)d_in[17]; const float* bv = (const float*)d_in[18];
  const float* wqp = (const float*)d_in[19]; const float* bqp = (const float*)d_in[20];
  const float* wkp = (const float*)d_in[21]; const float* bkp = (const float*)d_in[22];
  const float* wvp = (const float*)d_in[23]; const float* bvp = (const float*)d_in[24];
  const float* wpb = (const float*)d_in[25];
  const float* head_w = (const float*)d_in[26];
  const float* wo = (const float*)d_in[27]; const float* bo = (const float*)d_in[28];
  const float* wt1 = (const float*)d_in[29]; const float* bt1 = (const float*)d_in[30];
  const float* wt2 = (const float*)d_in[31]; const float* bt2 = (const float*)d_in[32];
  const float* wt3 = (const float*)d_in[33]; const float* bt3 = (const float*)d_in[34];
  const float* wbb = (const float*)d_in[35]; const float* bbb = (const float*)d_in[36];

  float* W = (float*)d_ws;
  float* scb   = W + OFF_SC;
  __half2* murs = (__half2*)(W + OFF_MURS);
  __half*  pbb  = (__half*)(W + OFF_PB);
  float* Pb    = W + OFF_P;
  float* qnb   = W + OFF_QN;
  float* knb   = W + OFF_KN;
  float* abuf  = W + OFF_A;
  float* catb  = W + OFF_CAT;
  float* ipab  = W + OFF_IPA;
  float* s0b   = W + OFF_IPA;     // alias: dead before loop's wo-GEMM
  float* Rb    = W + OFF_R;
  float* tb    = W + OFF_T;
  float* gammab= W + OFF_GAMMA;
  float* maskb = W + OFF_MASKB;
  float* bcat  = W + OFF_BCAT;
  __hip_bfloat16* WinitP = (__hip_bfloat16*)(W + OFF_WINITP);
  __hip_bfloat16* Wt1P   = (__hip_bfloat16*)(W + OFF_WT1P);
  __hip_bfloat16* Wt2P   = (__hip_bfloat16*)(W + OFF_WT2P);
  __hip_bfloat16* Wt3P   = (__hip_bfloat16*)(W + OFF_WT3P);
  __hip_bfloat16* WoP    = (__hip_bfloat16*)(W + OFF_WOP);
  __hip_bfloat16* WcatP  = (__hip_bfloat16*)(W + OFF_WCATP);
  float* Qp = W + OFF_QP;
  __hip_bfloat16* Kp = (__hip_bfloat16*)(W + OFF_KP);
  __hip_bfloat16* Vp = (__hip_bfloat16*)(W + OFF_VP);

  k_setup<<<9, 256, 0, stream>>>(bq,bk,bv,bqp,bkp,bvp, head_w, mask, bcat, gammab, maskb, Rb, tb);
  k_pack_cat<<<CSd*NPROJ/256, 256, 0, stream>>>(wq,wk,wv,wqp,wkp,wvp, WcatP);
  k_pack<<<256,  256, 0, stream>>>(w_init, CSd, CSd, WinitP);
  k_pack<<<1536, 256, 0, stream>>>(wo, CATd, CSd, WoP);
  k_pack<<<256,  256, 0, stream>>>(wt1, CSd, CSd, Wt1P);
  k_pack<<<256,  256, 0, stream>>>(wt2, CSd, CSd, Wt2P);
  k_pack<<<256,  256, 0, stream>>>(wt3, CSd, CSd, Wt3P);

  k_addln<<<Lq, 256, 0, stream>>>(s, nullptr, ln_s_g, ln_s_b, s0b);
  k_gemm_mfma<<<dim3(4,8), 256, 0, stream>>>(s0b, CSd, WinitP, CSd, b_init, scb, 0, nullptr);
  k_lnz_pb<<<Lq*Lq/64, 256, 0, stream>>>(z, ln_z_g, ln_z_b, wpb, murs, pbb);

  for (int it=0; it<8; ++it){
    k_gemm_mfma<<<dim3(18,8), 256, 0, stream>>>(scb, CSd, WcatP, NPROJ, bcat, Pb, 0, nullptr);
    k_packqkv<<<3072, 256, 0, stream>>>(Pb, Rb, tb, gammab, Qp, Kp, Vp, qnb, knb);
    k_attn<<<dim3(32,8), 256, 0, stream>>>(Qp, Kp, Vp, qnb, knb, pbb, maskb, gammab, Rb, tb, abuf, catb);
    k_opair<<<Lq, 256, 0, stream>>>(abuf, murs, z, ln_z_g, ln_z_b, catb);
    k_gemm_mfma<<<dim3(4,8), 256, 0, stream>>>(catb, CATd, WoP, CSd, bo, ipab, 0, nullptr);
    k_mega<<<32, 256, 0, stream>>>(scb, ipab, ln_ipa_g, ln_ipa_b,
                                   Wt1P, bt1, Wt2P, bt2, Wt3P, bt3,
                                   ln_tr_g, ln_tr_b, mask, wbb, bbb, Rb, tb);
  }
  k_writeout<<<536, 256, 0, stream>>>(scb, Rb, tb, (float*)d_out);
}

// Round 5
// 1253.199 us; speedup vs baseline: 2.3186x; 1.3767x over previous
//
#include <hip/hip_runtime.h>
#include <hip/hip_bf16.h>
#include <hip/hip_fp16.h>
#include <math.h>

#define Lq 512
#define CSd 256
#define CZd 128
#define Hd 8
#define CHd 32
#define PQd 4
#define PVd 8
#define CATd 1536
#define NPROJ 1152

typedef __attribute__((ext_vector_type(4))) float floatx4;
typedef __attribute__((ext_vector_type(8))) short shortx8;

// ---------------- ws layout (float offsets) ----------------
#define OFF_SC      0         // 131072
#define OFF_PB      393216    // 1048576 (half)
#define OFF_P       1441792   // 589824
#define OFF_QN      2031616   // 4096
#define OFF_KN      2035712   // 4096
#define OFF_A16     2039808   // 2097152: first half = a16hi (2^21 bf16), second = a16lo
#define OFF_CAT     4136960   // 786432
#define OFF_S0      4923392   // 131072
#define OFF_R       5054464   // 4608
#define OFF_T       5059072   // 1536
#define OFF_GAMMA   5060608   // 8
#define OFF_MASKB   5060616   // 512
#define OFF_BCAT    5061128   // 1152
#define OFF_WINITP  5062280   // 65536
#define OFF_WT1P    5127816   // 65536
#define OFF_WT2P    5193352   // 65536
#define OFF_WT3P    5258888   // 65536
#define OFF_WOP     5324424   // 393216
#define OFF_WCATP   5717640   // 294912
#define OFF_QP      6012552   // 262144 (fp32)
#define OFF_KP      6274696   // 262144 (=524288 bf16)
#define OFF_VP      6536840   // 262144 (=524288 bf16)
#define OFF_ZNT     6798984   // 16777216 (=33554432 bf16)  [i][c][j] bf16
// total ~94.3 MB << 512 MB ws

#define WLC 0.57735026918962576f
#define WCC 0.23570226039551584f
#define ISC 0.17677669529663687f

__device__ __forceinline__ float wave_sum(float v){
  #pragma unroll
  for (int m=32; m; m>>=1) v += __shfl_xor(v, m);
  return v;
}
__device__ __forceinline__ short f2bf(float v){
  __hip_bfloat16 h = (__hip_bfloat16)v;
  return __builtin_bit_cast(short, h);
}
__device__ __forceinline__ float bf2f(short s){
  unsigned u = ((unsigned)(unsigned short)s) << 16;
  return __builtin_bit_cast(float, u);
}

// ------------- setup: bcat/gamma/maskbias/R/t -------------
__global__ __launch_bounds__(256) void k_setup(
    const float* __restrict__ bq, const float* __restrict__ bk, const float* __restrict__ bv,
    const float* __restrict__ bqp, const float* __restrict__ bkp, const float* __restrict__ bvp,
    const float* __restrict__ head_w, const float* __restrict__ mask,
    float* __restrict__ bcat, float* __restrict__ gamma,
    float* __restrict__ maskb, float* __restrict__ R, float* __restrict__ t){
  int k = blockIdx.x*256 + threadIdx.x;
  if (k < NPROJ){
    float v;
    if      (k < 256) v = bq[k];
    else if (k < 512) v = bk[k-256];
    else if (k < 768) v = bv[k-512];
    else if (k < 864) v = bqp[k-768];
    else if (k < 960) v = bkp[k-864];
    else              v = bvp[k-960];
    bcat[k] = v;
    return;
  }
  k -= NPROJ;
  if (k < Hd){ gamma[k] = log1pf(expf(head_w[k])); return; }
  k -= Hd;
  if (k < Lq){ maskb[k] = (mask[k] - 1.f)*1e9f; return; }
  k -= Lq;
  if (k < Lq){
    #pragma unroll
    for (int ii=0; ii<9; ii++) R[k*9+ii] = (ii==0||ii==4||ii==8) ? 1.f : 0.f;
    t[k*3] = 0.f; t[k*3+1] = 0.f; t[k*3+2] = 0.f;
  }
}

// ------------- pack [K,N] fp32 weight into MFMA-B hi/lo bf16 layout -------------
__global__ __launch_bounds__(256) void k_pack(
    const float* __restrict__ W, int K, int N, __hip_bfloat16* __restrict__ out){
  int idx = blockIdx.x*256 + threadIdx.x;
  if (idx >= K*N) return;
  int j = idx & 7, lane = (idx>>3) & 63, rest = idx >> 9;
  int nt = N >> 4;
  int tn = rest % nt, tk = rest / nt;
  int k = tk*32 + (lane>>4)*8 + j;
  int n = tn*16 + (lane&15);
  float v = W[(size_t)k*N + n];
  short h = f2bf(v);
  short l = f2bf(v - bf2f(h));
  size_t base = (size_t)rest*1024 + (idx & 511);
  out[base]       = __builtin_bit_cast(__hip_bfloat16, h);
  out[base + 512] = __builtin_bit_cast(__hip_bfloat16, l);
}

// ------------- pack the concatenated projection weight (virtual [256,1152]) -------------
__global__ __launch_bounds__(256) void k_pack_cat(
    const float* __restrict__ wq, const float* __restrict__ wk, const float* __restrict__ wv,
    const float* __restrict__ wqp, const float* __restrict__ wkp, const float* __restrict__ wvp,
    __hip_bfloat16* __restrict__ out){
  int idx = blockIdx.x*256 + threadIdx.x;
  if (idx >= CSd*NPROJ) return;
  int j = idx & 7, lane = (idx>>3) & 63, rest = idx >> 9;
  const int nt = NPROJ >> 4;
  int tn = rest % nt, tk = rest / nt;
  int k = tk*32 + (lane>>4)*8 + j;
  int n = tn*16 + (lane&15);
  float v;
  if      (n < 256) v = wq[k*256 + n];
  else if (n < 512) v = wk[k*256 + n-256];
  else if (n < 768) v = wv[k*256 + n-512];
  else if (n < 864) v = wqp[k*96 + n-768];
  else if (n < 960) v = wkp[k*96 + n-864];
  else              v = wvp[k*192 + n-960];
  short h = f2bf(v);
  short l = f2bf(v - bf2f(h));
  size_t base = (size_t)rest*1024 + (idx & 511);
  out[base]       = __builtin_bit_cast(__hip_bfloat16, h);
  out[base + 512] = __builtin_bit_cast(__hip_bfloat16, l);
}

// ------------- split-precision MFMA GEMM -------------
__global__ __launch_bounds__(256) void k_gemm_mfma(
    const float* __restrict__ A, int K,
    const __hip_bfloat16* __restrict__ Bp, int N,
    const float* __restrict__ bias,
    float* __restrict__ Cf,
    int relu, const float* __restrict__ rowscale){
  int tid = threadIdx.x;
  int wave = tid>>6, lane = tid&63;
  int i0 = blockIdx.y*64 + wave*16;
  int n0 = blockIdx.x*64;
  int quad = lane>>4, l16 = lane&15;
  floatx4 acc[4] = {};
  const int ntiles = N >> 4;
  const float* arow = A + (size_t)(i0 + l16)*K + quad*8;
  const __hip_bfloat16* bbase = Bp + ((size_t)(n0>>4))*1024 + (size_t)(lane&63)*8;
  for (int k0=0; k0<K; k0+=32){
    float4 v0 = *(const float4*)(arow + k0);
    float4 v1 = *(const float4*)(arow + k0 + 4);
    float av[8] = {v0.x,v0.y,v0.z,v0.w,v1.x,v1.y,v1.z,v1.w};
    shortx8 ahi, alo;
    #pragma unroll
    for (int j=0; j<8; j++){
      short h = f2bf(av[j]);
      ahi[j] = h;
      alo[j] = f2bf(av[j] - bf2f(h));
    }
    const __hip_bfloat16* bt = bbase + (size_t)(k0>>5)*ntiles*1024;
    #pragma unroll
    for (int s=0; s<4; s++){
      shortx8 bhi = *(const shortx8*)(bt + s*1024);
      shortx8 blo = *(const shortx8*)(bt + s*1024 + 512);
      acc[s] = __builtin_amdgcn_mfma_f32_16x16x32_bf16(ahi, bhi, acc[s], 0, 0, 0);
      acc[s] = __builtin_amdgcn_mfma_f32_16x16x32_bf16(alo, bhi, acc[s], 0, 0, 0);
      acc[s] = __builtin_amdgcn_mfma_f32_16x16x32_bf16(ahi, blo, acc[s], 0, 0, 0);
    }
  }
  #pragma unroll
  for (int s=0; s<4; s++){
    int n = n0 + s*16 + l16;
    float bs = bias ? bias[n] : 0.f;
    #pragma unroll
    for (int r=0; r<4; r++){
      int m = i0 + quad*4 + r;
      float v = acc[s][r] + bs;
      if (relu) v = fmaxf(v, 0.f);
      if (rowscale) v *= rowscale[m];
      Cf[(size_t)m*N + n] = v;
    }
  }
}

// ------------- LN over CS=256 row -------------
__global__ __launch_bounds__(256) void k_addln(
    const float* __restrict__ x, const float* __restrict__ y,
    const float* __restrict__ g, const float* __restrict__ b,
    float* __restrict__ out){
  __shared__ float red[4];
  int row = blockIdx.x, tid = threadIdx.x;
  float v = x[row*CSd + tid];
  if (y) v += y[row*CSd + tid];
  int wid = tid>>6, lane = tid&63;
  float s = wave_sum(v);
  if (lane==0) red[wid] = s;
  __syncthreads();
  float mu = (red[0]+red[1]+red[2]+red[3]) * (1.f/CSd);
  __syncthreads();
  float d = v - mu;
  float s2 = wave_sum(d*d);
  if (lane==0) red[wid] = s2;
  __syncthreads();
  float var = (red[0]+red[1]+red[2]+red[3]) * (1.f/CSd);
  float rs = rsqrtf(var + 1e-5f);
  out[row*CSd + tid] = d*rs*g[tid] + b[tid];
}

// ------------- zn LN: pair_bias (half) + zn16 transposed bf16 [i][c][j] -------------
__global__ __launch_bounds__(256) void k_lnz_pb(
    const float* __restrict__ z, const float* __restrict__ g, const float* __restrict__ b,
    const float* __restrict__ wpb, __half* __restrict__ pb, __hip_bfloat16* __restrict__ znt){
  __shared__ float Zt[64*129];
  __shared__ float gwt[8][132];
  __shared__ float AB[16];
  __shared__ float red[64*4*11];
  __shared__ float mvl[64][2];
  int tid = threadIdx.x;
  size_t row0 = (size_t)blockIdx.x*64;
  int ib = (int)(row0 >> 9), j0 = (int)(row0 & 511);
  const float4* zsrc = (const float4*)(z + row0*CZd);
  #pragma unroll
  for (int it=0; it<8; it++){
    int idx = tid + it*256;
    int rr = idx>>5, qq = idx&31;
    float4 v = zsrc[idx];
    float* dst = &Zt[rr*129 + qq*4];
    dst[0]=v.x; dst[1]=v.y; dst[2]=v.z; dst[3]=v.w;
  }
  for (int idx=tid; idx<1024; idx+=256){
    int h = idx&7, c = idx>>3;
    gwt[h][c] = g[c]*wpb[c*8+h];
  }
  if (tid < 16){
    int h = tid&7; const float* src = (tid<8) ? g : b;
    float s = 0.f;
    for (int c=0; c<128; c++) s += src[c]*wpb[c*8+h];
    AB[tid] = s;
  }
  __syncthreads();
  int q = tid>>6, r = tid&63;
  const float* zr = &Zt[r*129 + q*32];
  float zv[32];
  #pragma unroll
  for (int t=0; t<32; t++) zv[t] = zr[t];
  float S1=0.f, S2=0.f;
  #pragma unroll
  for (int t=0; t<32; t++){ S1 += zv[t]; S2 += zv[t]*zv[t]; }
  float* rd = &red[(r*4+q)*11];
  rd[8]=S1; rd[9]=S2;
  #pragma unroll
  for (int h=0; h<8; h++){
    const float4* gw4 = (const float4*)&gwt[h][q*32];
    float d = 0.f;
    #pragma unroll
    for (int t4=0; t4<8; t4++){
      float4 gv = gw4[t4];
      d += zv[t4*4]*gv.x + zv[t4*4+1]*gv.y + zv[t4*4+2]*gv.z + zv[t4*4+3]*gv.w;
    }
    rd[h] = d;
  }
  __syncthreads();
  if (tid < 64){
    int rr = tid;
    const float* r0 = &red[rr*44];
    float acc[10];
    #pragma unroll
    for (int v=0; v<10; v++) acc[v] = r0[v] + r0[11+v] + r0[22+v] + r0[33+v];
    float mu  = acc[8]*(1.f/128.f);
    float var = acc[9]*(1.f/128.f) - mu*mu;
    float rs  = rsqrtf(var + 1e-5f);
    mvl[rr][0] = mu; mvl[rr][1] = rs;
    int j = j0 + rr;
    #pragma unroll
    for (int h=0; h<8; h++){
      float pbv = rs*(acc[h] - mu*AB[h]) + AB[8+h];
      pb[((size_t)(h*Lq+ib))*Lq + j] = __float2half(pbv);
    }
  }
  __syncthreads();
  // second pass: write zn bf16 transposed [i][c][j]
  #pragma unroll
  for (int it2=0; it2<32; it2++){
    int idx = it2*256 + tid;
    int c = idx >> 6, jo = idx & 63;
    float mu = mvl[jo][0], rs = mvl[jo][1];
    float zn = (Zt[jo*129 + c] - mu)*rs*g[c] + b[c];
    znt[((size_t)ib*128 + c)*512 + j0 + jo] = (__hip_bfloat16)zn;
  }
}

// ------------- pack Q'/K'/V' in MFMA layouts, compute qn/kn -------------
__global__ __launch_bounds__(256) void k_packqkv(
    const float* __restrict__ P, const float* __restrict__ R, const float* __restrict__ t,
    const float* __restrict__ gamma,
    float* __restrict__ Qp, __hip_bfloat16* __restrict__ Kp, __hip_bfloat16* __restrict__ Vp,
    float* __restrict__ qn, float* __restrict__ kn){
  int idx = blockIdx.x*256 + threadIdx.x;   // 3*262144
  int region = idx >> 18;
  int rem = idx & 262143;
  int h = rem >> 15;
  int r2 = rem & 32767;
  if (region == 0){
    int j = r2 >> 6, f = r2 & 63;
    float val = 0.f;
    if (f < 32) val = P[(size_t)j*NPROJ + 256 + h*CHd + f];
    else if (f < 44){
      int p = (f-32)/3, ax = (f-32)%3;
      const float* kp = P + (size_t)j*NPROJ + 864 + h*12 + p*3;
      const float* Rr = R + j*9 + ax*3;
      val = Rr[0]*kp[0] + Rr[1]*kp[1] + Rr[2]*kp[2] + t[j*3+ax];
    }
    short hi = f2bf(val), lo = f2bf(val - bf2f(hi));
    int kc = f>>5, jt = j>>4, l16 = j&15, fl = f&31, quad = fl>>3, jj = f&7;
    size_t base = (size_t)((h*2+kc)*32 + jt)*1024 + (quad*16+l16)*8 + jj;
    Kp[base] = __builtin_bit_cast(__hip_bfloat16, hi);
    Kp[base+512] = __builtin_bit_cast(__hip_bfloat16, lo);
    if (f == 0){
      const float* Rm = R + j*9; const float* tv = t + j*3;
      float acc = 0.f;
      #pragma unroll
      for (int p=0; p<PQd; p++){
        const float* kp = P + (size_t)j*NPROJ + 864 + h*12 + p*3;
        #pragma unroll
        for (int ax=0; ax<3; ax++){
          float g = Rm[ax*3]*kp[0] + Rm[ax*3+1]*kp[1] + Rm[ax*3+2]*kp[2] + tv[ax];
          acc += g*g;
        }
      }
      kn[j*Hd + h] = acc;
    }
  } else if (region == 1){
    int j = r2 >> 6, n = r2 & 63;
    float val = 0.f;
    if (n < 32) val = P[(size_t)j*NPROJ + 512 + h*CHd + n];
    else if (n < 56){
      int p = (n-32)/3, ax = (n-32)%3;
      const float* vp = P + (size_t)j*NPROJ + 960 + h*24 + p*3;
      const float* Rr = R + j*9 + ax*3;
      val = Rr[0]*vp[0] + Rr[1]*vp[1] + Rr[2]*vp[2] + t[j*3+ax];
    }
    short hi = f2bf(val), lo = f2bf(val - bf2f(hi));
    int kc2 = j>>5, w = n>>4, l16 = n&15, jl = j&31, quad = jl>>3, jj = j&7;
    size_t base = (size_t)((h*16+kc2)*4 + w)*1024 + (quad*16+l16)*8 + jj;
    Vp[base] = __builtin_bit_cast(__hip_bfloat16, hi);
    Vp[base+512] = __builtin_bit_cast(__hip_bfloat16, lo);
  } else {
    int i = r2 >> 6, f = r2 & 63;
    float val = 0.f;
    if (f < 32) val = P[(size_t)i*NPROJ + h*CHd + f] * (WLC*ISC);
    else if (f < 44){
      int p = (f-32)/3, ax = (f-32)%3;
      const float* qp = P + (size_t)i*NPROJ + 768 + h*12 + p*3;
      const float* Rr = R + i*9 + ax*3;
      float g = Rr[0]*qp[0] + Rr[1]*qp[1] + Rr[2]*qp[2] + t[i*3+ax];
      val = g * (WLC*WCC*gamma[h]);
    }
    Qp[((size_t)h*512 + i)*64 + f] = val;
    if (f == 0){
      const float* Rm = R + i*9; const float* tv = t + i*3;
      float acc = 0.f;
      #pragma unroll
      for (int p=0; p<PQd; p++){
        const float* qp = P + (size_t)i*NPROJ + 768 + h*12 + p*3;
        #pragma unroll
        for (int ax=0; ax<3; ax++){
          float g = Rm[ax*3]*qp[0] + Rm[ax*3+1]*qp[1] + Rm[ax*3+2]*qp[2] + tv[ax];
          acc += g*g;
        }
      }
      qn[i*Hd + h] = acc;
    }
  }
}

// ------------- fused attention: QK^T + softmax + A@V' + optl/onrm; emits a16 hi/lo -------------
__global__ __launch_bounds__(256) void k_attn(
    const float* __restrict__ Qp, const __hip_bfloat16* __restrict__ Kp,
    const __hip_bfloat16* __restrict__ Vp,
    const float* __restrict__ qn, const float* __restrict__ kn,
    const __half* __restrict__ pb, const float* __restrict__ maskb,
    const float* __restrict__ gamma,
    const float* __restrict__ R, const float* __restrict__ t,
    __hip_bfloat16* __restrict__ a16hi, __hip_bfloat16* __restrict__ a16lo,
    float* __restrict__ cat){
  __shared__ float At[16][516];
  __shared__ float Ot[16][36];
  __shared__ float red1[16][16];
  __shared__ float red2[16][16];
  __shared__ float invL[16];
  __shared__ float qnL[16];
  int tid = threadIdx.x;
  int i0 = blockIdx.x*16, h = blockIdx.y;
  int wave = tid>>6, lane = tid&63, quad = lane>>4, l16 = lane&15;
  float gam = gamma[h];
  float coef = 0.5f*WLC*WCC*gam;
  if (tid < 16) qnL[tid] = qn[(i0+tid)*Hd + h];
  __syncthreads();
  // ---- QK phase ----
  const float* qrow = Qp + ((size_t)h*512 + i0 + l16)*64 + quad*8;
  for (int it=0; it<8; it++){
    int jt = it*4 + wave;
    floatx4 acc = {};
    #pragma unroll
    for (int kc=0; kc<2; kc++){
      float4 v0 = *(const float4*)(qrow + kc*32);
      float4 v1 = *(const float4*)(qrow + kc*32 + 4);
      float av[8] = {v0.x,v0.y,v0.z,v0.w,v1.x,v1.y,v1.z,v1.w};
      shortx8 ahi, alo;
      #pragma unroll
      for (int j=0; j<8; j++){
        short hh = f2bf(av[j]);
        ahi[j] = hh; alo[j] = f2bf(av[j] - bf2f(hh));
      }
      const __hip_bfloat16* bt = Kp + (size_t)((h*2+kc)*32 + jt)*1024 + lane*8;
      shortx8 bhi = *(const shortx8*)bt;
      shortx8 blo = *(const shortx8*)(bt + 512);
      acc = __builtin_amdgcn_mfma_f32_16x16x32_bf16(ahi, bhi, acc, 0, 0, 0);
      acc = __builtin_amdgcn_mfma_f32_16x16x32_bf16(alo, bhi, acc, 0, 0, 0);
      acc = __builtin_amdgcn_mfma_f32_16x16x32_bf16(ahi, blo, acc, 0, 0, 0);
    }
    int j = jt*16 + l16;
    float knj = kn[j*Hd + h];
    float mbj = maskb[j];
    #pragma unroll
    for (int r=0; r<4; r++){
      int i = quad*4 + r;
      float pbv = __half2float(pb[((size_t)(h*Lq) + i0 + i)*Lq + j]);
      At[i][j] = acc[r] + WLC*pbv + mbj - coef*(qnL[i] + knj);
    }
  }
  __syncthreads();
  // ---- softmax ----
  int srow = tid>>4, sseg = tid&15;
  {
    float m = -1e30f;
    #pragma unroll 8
    for (int k2=0; k2<32; k2++) m = fmaxf(m, At[srow][sseg + k2*16]);
    red1[srow][sseg] = m;
  }
  __syncthreads();
  float mrow = red1[srow][0];
  #pragma unroll
  for (int c=1;c<16;c++) mrow = fmaxf(mrow, red1[srow][c]);
  {
    float ssum = 0.f;
    #pragma unroll 8
    for (int k2=0; k2<32; k2++){
      int cc = sseg + k2*16;
      float e = __expf(At[srow][cc]-mrow);
      At[srow][cc] = e; ssum += e;
    }
    red2[srow][sseg] = ssum;
  }
  __syncthreads();
  if (tid < 16){
    float s=0.f;
    #pragma unroll
    for (int c=0;c<16;c++) s += red2[tid][c];
    invL[tid] = 1.f/s;
  }
  __syncthreads();
  // normalize + write a16 hi/lo in MFMA-A-compact layout [i][kt][h][32]
  for (int idx2=tid; idx2<8192; idx2+=256){
    int rr = idx2>>9, cc = idx2&511;
    float v = At[rr][cc]*invL[rr];
    At[rr][cc] = v;
    short hv = f2bf(v);
    short lv = f2bf(v - bf2f(hv));
    size_t ai = (((size_t)(i0+rr)*16 + (cc>>5))*8 + h)*32 + (cc&31);
    a16hi[ai] = __builtin_bit_cast(__hip_bfloat16, hv);
    a16lo[ai] = __builtin_bit_cast(__hip_bfloat16, lv);
  }
  __syncthreads();
  // ---- AV phase ----
  floatx4 acc2 = {};
  for (int kc2=0; kc2<16; kc2++){
    const float* ar = &At[l16][kc2*32 + quad*8];
    float4 v0 = *(const float4*)ar;
    float4 v1 = *(const float4*)(ar+4);
    float av[8] = {v0.x,v0.y,v0.z,v0.w,v1.x,v1.y,v1.z,v1.w};
    shortx8 ahi, alo;
    #pragma unroll
    for (int j=0; j<8; j++){
      short hh = f2bf(av[j]);
      ahi[j] = hh; alo[j] = f2bf(av[j] - bf2f(hh));
    }
    const __hip_bfloat16* bt = Vp + (size_t)((h*16+kc2)*4 + wave)*1024 + lane*8;
    shortx8 bhi = *(const shortx8*)bt;
    shortx8 blo = *(const shortx8*)(bt + 512);
    acc2 = __builtin_amdgcn_mfma_f32_16x16x32_bf16(ahi, bhi, acc2, 0, 0, 0);
    acc2 = __builtin_amdgcn_mfma_f32_16x16x32_bf16(alo, bhi, acc2, 0, 0, 0);
    acc2 = __builtin_amdgcn_mfma_f32_16x16x32_bf16(ahi, blo, acc2, 0, 0, 0);
  }
  {
    int n = wave*16 + l16;
    #pragma unroll
    for (int r=0;r<4;r++){
      int i = quad*4+r;
      if (n < 32) cat[(size_t)(i0+i)*CATd + h*CHd + n] = acc2[r];
      else        Ot[i][n-32] = acc2[r];
    }
  }
  __syncthreads();
  if (tid < 128){
    int i = tid>>3, p = tid&7, gi = i0+i;
    float o0 = Ot[i][p*3], o1 = Ot[i][p*3+1], o2 = Ot[i][p*3+2];
    float d0 = o0 - t[gi*3], d1 = o1 - t[gi*3+1], d2 = o2 - t[gi*3+2];
    const float* Rm = R + gi*9;
    float l0 = Rm[0]*d0 + Rm[3]*d1 + Rm[6]*d2;
    float l1 = Rm[1]*d0 + Rm[4]*d1 + Rm[7]*d2;
    float l2 = Rm[2]*d0 + Rm[5]*d1 + Rm[8]*d2;
    float* cr = cat + (size_t)gi*CATd;
    cr[256 + h*24 + p*3]   = l0;
    cr[256 + h*24 + p*3+1] = l1;
    cr[256 + h*24 + p*3+2] = l2;
    cr[448 + h*8 + p] = sqrtf(l0*l0 + l1*l1 + l2*l2 + 1e-8f);
  }
}

// ------------- opair = a @ zn via MFMA (no LDS) -------------
__global__ __launch_bounds__(256) void k_opair_mfma(
    const __hip_bfloat16* __restrict__ a16hi, const __hip_bfloat16* __restrict__ a16lo,
    const __hip_bfloat16* __restrict__ znt, float* __restrict__ cat){
  int i = blockIdx.x;
  int tid = threadIdx.x;
  int wave = tid>>6, lane = tid&63, quad = lane>>4, l16 = lane&15;
  int nt0 = wave*2, nt1 = wave*2+1;
  floatx4 acc0 = {}, acc1 = {};
  const __hip_bfloat16* abase_h = a16hi + ((size_t)i*16*8 + (l16&7))*32 + quad*8;
  const __hip_bfloat16* abase_l = a16lo + ((size_t)i*16*8 + (l16&7))*32 + quad*8;
  const __hip_bfloat16* zb0 = znt + ((size_t)i*128 + nt0*16 + l16)*512 + quad*8;
  const __hip_bfloat16* zb1 = znt + ((size_t)i*128 + nt1*16 + l16)*512 + quad*8;
  #pragma unroll
  for (int kt=0; kt<16; kt++){
    shortx8 ah = *(const shortx8*)(abase_h + kt*256);
    shortx8 al = *(const shortx8*)(abase_l + kt*256);
    shortx8 b0 = *(const shortx8*)(zb0 + kt*32);
    shortx8 b1 = *(const shortx8*)(zb1 + kt*32);
    acc0 = __builtin_amdgcn_mfma_f32_16x16x32_bf16(ah, b0, acc0, 0, 0, 0);
    acc0 = __builtin_amdgcn_mfma_f32_16x16x32_bf16(al, b0, acc0, 0, 0, 0);
    acc1 = __builtin_amdgcn_mfma_f32_16x16x32_bf16(ah, b1, acc1, 0, 0, 0);
    acc1 = __builtin_amdgcn_mfma_f32_16x16x32_bf16(al, b1, acc1, 0, 0, 0);
  }
  if (quad < 2){
    float* cr = cat + (size_t)i*CATd + 512;
    #pragma unroll
    for (int r=0; r<4; r++){
      int h = quad*4 + r;
      cr[h*CZd + nt0*16 + l16] = acc0[r];
      cr[h*CZd + nt1*16 + l16] = acc1[r];
    }
  }
}

// ------------- mega: wo-GEMM + LN + 3 GEMMs + LN + upd + frame update -------------
__device__ __forceinline__ void gemm_stage(
    const float (*X)[260], float (*Y)[260],
    const __hip_bfloat16* __restrict__ Wp, const float* __restrict__ bias,
    bool relu, int tid){
  int wave = tid>>6, lane = tid&63, quad = lane>>4, l16 = lane&15;
  floatx4 acc[4] = {};
  for (int kc=0; kc<8; kc++){
    const float* xr = &X[l16][kc*32 + quad*8];
    float4 v0 = *(const float4*)xr;
    float4 v1 = *(const float4*)(xr+4);
    float av[8] = {v0.x,v0.y,v0.z,v0.w,v1.x,v1.y,v1.z,v1.w};
    shortx8 ahi, alo;
    #pragma unroll
    for (int j=0; j<8; j++){
      short hh = f2bf(av[j]);
      ahi[j] = hh; alo[j] = f2bf(av[j] - bf2f(hh));
    }
    #pragma unroll
    for (int ns=0; ns<4; ns++){
      const __hip_bfloat16* bt = Wp + (size_t)(kc*16 + wave*4 + ns)*1024 + lane*8;
      shortx8 bhi = *(const shortx8*)bt;
      shortx8 blo = *(const shortx8*)(bt + 512);
      acc[ns] = __builtin_amdgcn_mfma_f32_16x16x32_bf16(ahi, bhi, acc[ns], 0, 0, 0);
      acc[ns] = __builtin_amdgcn_mfma_f32_16x16x32_bf16(alo, bhi, acc[ns], 0, 0, 0);
      acc[ns] = __builtin_amdgcn_mfma_f32_16x16x32_bf16(ahi, blo, acc[ns], 0, 0, 0);
    }
  }
  #pragma unroll
  for (int ns=0; ns<4; ns++){
    int n = wave*64 + ns*16 + l16;
    float bs = bias[n];
    #pragma unroll
    for (int r=0;r<4;r++){
      float v = acc[ns][r] + bs;
      if (relu) v = fmaxf(v, 0.f);
      Y[quad*4+r][n] = v;
    }
  }
}

__global__ __launch_bounds__(256) void k_mega(
    float* __restrict__ scb, const float* __restrict__ cat,
    const __hip_bfloat16* __restrict__ Wo, const float* __restrict__ bo,
    const float* __restrict__ gi_, const float* __restrict__ bi_,
    const __hip_bfloat16* __restrict__ W1, const float* __restrict__ c1,
    const __hip_bfloat16* __restrict__ W2, const float* __restrict__ c2,
    const __hip_bfloat16* __restrict__ W3, const float* __restrict__ c3,
    const float* __restrict__ gt_, const float* __restrict__ bt_,
    const float* __restrict__ mask,
    const float* __restrict__ wbb, const float* __restrict__ bbb,
    float* __restrict__ R, float* __restrict__ t){
  __shared__ float As[16][260], Bs[16][260], Cs[16][260];
  __shared__ float rA[16][17], rB[16][17];
  __shared__ float mv[16][2];
  __shared__ float u6[16][6];
  int tid = threadIdx.x;
  int i0 = blockIdx.x*16;
  int wave = tid>>6, lane = tid&63, quad = lane>>4, l16 = lane&15;
  int r = tid>>4, c0 = (tid&15)*16;
  float v[16];
  // phase A: ipa = cat @ Wo + bo  -> Bs
  {
    floatx4 acc[4] = {};
    const float* arow = cat + (size_t)(i0 + l16)*CATd + quad*8;
    const __hip_bfloat16* bbase = Wo + (size_t)(wave*4)*1024 + (size_t)lane*8;
    for (int k0=0; k0<CATd; k0+=32){
      float4 v0 = *(const float4*)(arow + k0);
      float4 v1 = *(const float4*)(arow + k0 + 4);
      float av[8] = {v0.x,v0.y,v0.z,v0.w,v1.x,v1.y,v1.z,v1.w};
      shortx8 ahi, alo;
      #pragma unroll
      for (int j=0; j<8; j++){
        short hh = f2bf(av[j]);
        ahi[j] = hh; alo[j] = f2bf(av[j] - bf2f(hh));
      }
      const __hip_bfloat16* bt = bbase + (size_t)(k0>>5)*16*1024;
      #pragma unroll
      for (int s=0; s<4; s++){
        shortx8 bhi = *(const shortx8*)(bt + s*1024);
        shortx8 blo = *(const shortx8*)(bt + s*1024 + 512);
        acc[s] = __builtin_amdgcn_mfma_f32_16x16x32_bf16(ahi, bhi, acc[s], 0, 0, 0);
        acc[s] = __builtin_amdgcn_mfma_f32_16x16x32_bf16(alo, bhi, acc[s], 0, 0, 0);
        acc[s] = __builtin_amdgcn_mfma_f32_16x16x32_bf16(ahi, blo, acc[s], 0, 0, 0);
      }
    }
    #pragma unroll
    for (int s=0; s<4; s++){
      int n = wave*64 + s*16 + l16;
      float bs = bo[n];
      #pragma unroll
      for (int rr=0; rr<4; rr++) Bs[quad*4+rr][n] = acc[s][rr] + bs;
    }
  }
  __syncthreads();
  // stage 0: LN(sc + ipa)
  {
    const float* sr = scb + (size_t)(i0+r)*CSd + c0;
    float s1=0.f, s2=0.f;
    #pragma unroll
    for (int k2=0;k2<16;k2++){ float x = sr[k2] + Bs[r][c0+k2]; v[k2]=x; s1+=x; s2+=x*x; }
    rA[r][tid&15]=s1; rB[r][tid&15]=s2;
  }
  __syncthreads();
  if (tid<16){
    float s1=0.f,s2=0.f;
    #pragma unroll
    for (int c=0;c<16;c++){ s1+=rA[tid][c]; s2+=rB[tid][c]; }
    float mu = s1*(1.f/CSd), var = s2*(1.f/CSd) - mu*mu;
    mv[tid][0]=mu; mv[tid][1]=rsqrtf(var+1e-5f);
  }
  __syncthreads();
  {
    float mu=mv[r][0], rs=mv[r][1];
    #pragma unroll
    for (int k2=0;k2<16;k2++) As[r][c0+k2] = (v[k2]-mu)*rs*gi_[c0+k2] + bi_[c0+k2];
  }
  __syncthreads();
  gemm_stage(As, Bs, W1, c1, true, tid);
  __syncthreads();
  gemm_stage(Bs, Cs, W2, c2, true, tid);
  __syncthreads();
  gemm_stage(Cs, Bs, W3, c3, false, tid);
  __syncthreads();
  // stage 4: LN(sc_new + tr3*mask)
  {
    float mk = mask[i0+r];
    float s1=0.f, s2=0.f;
    #pragma unroll
    for (int k2=0;k2<16;k2++){ float x = As[r][c0+k2] + Bs[r][c0+k2]*mk; v[k2]=x; s1+=x; s2+=x*x; }
    rA[r][tid&15]=s1; rB[r][tid&15]=s2;
  }
  __syncthreads();
  if (tid<16){
    float s1=0.f,s2=0.f;
    #pragma unroll
    for (int c=0;c<16;c++){ s1+=rA[tid][c]; s2+=rB[tid][c]; }
    float mu = s1*(1.f/CSd), var = s2*(1.f/CSd) - mu*mu;
    mv[tid][0]=mu; mv[tid][1]=rsqrtf(var+1e-5f);
  }
  __syncthreads();
  {
    float mu=mv[r][0], rs=mv[r][1];
    float* out = scb + (size_t)(i0+r)*CSd + c0;
    #pragma unroll
    for (int k2=0;k2<16;k2++){
      float o = (v[k2]-mu)*rs*gt_[c0+k2] + bt_[c0+k2];
      As[r][c0+k2] = o;
      out[k2] = o;
    }
  }
  __syncthreads();
  // stage 5: upd + quat update
  if (tid < 96){
    int rr = tid/6, o = tid%6;
    float acc = bbb[o];
    for (int k2=0;k2<CSd;k2++) acc += As[rr][k2]*wbb[k2*6+o];
    u6[rr][o] = acc;
  }
  __syncthreads();
  if (tid < 16){
    int gidx = i0 + tid;
    float bq = u6[tid][0], cq = u6[tid][1], dq = u6[tid][2];
    float norm = sqrtf(1.f + bq*bq + cq*cq + dq*dq);
    float a = 1.f/norm, b_ = bq/norm, c_ = cq/norm, d_ = dq/norm;
    float dR[9];
    dR[0] = a*a + b_*b_ - c_*c_ - d_*d_; dR[1] = 2.f*(b_*c_ - a*d_); dR[2] = 2.f*(b_*d_ + a*c_);
    dR[3] = 2.f*(b_*c_ + a*d_); dR[4] = a*a - b_*b_ + c_*c_ - d_*d_; dR[5] = 2.f*(c_*d_ - a*b_);
    dR[6] = 2.f*(b_*d_ - a*c_); dR[7] = 2.f*(c_*d_ + a*b_); dR[8] = a*a - b_*b_ - c_*c_ + d_*d_;
    float mk = mask[gidx];
    float dt0 = u6[tid][3]*mk, dt1 = u6[tid][4]*mk, dt2 = u6[tid][5]*mk;
    float Rm[9];
    #pragma unroll
    for (int ii=0; ii<9; ii++) Rm[ii] = R[gidx*9+ii];
    t[gidx*3]   += Rm[0]*dt0 + Rm[1]*dt1 + Rm[2]*dt2;
    t[gidx*3+1] += Rm[3]*dt0 + Rm[4]*dt1 + Rm[5]*dt2;
    t[gidx*3+2] += Rm[6]*dt0 + Rm[7]*dt1 + Rm[8]*dt2;
    #pragma unroll
    for (int ii=0; ii<3; ii++)
      #pragma unroll
      for (int jj=0; jj<3; jj++)
        R[gidx*9 + ii*3 + jj] = Rm[ii*3]*dR[jj] + Rm[ii*3+1]*dR[3+jj] + Rm[ii*3+2]*dR[6+jj];
  }
}

// ------------- final output write -------------
__global__ __launch_bounds__(256) void k_writeout(
    const float* __restrict__ sc, const float* __restrict__ R, const float* __restrict__ t,
    float* __restrict__ out){
  int idx = blockIdx.x*256 + threadIdx.x;
  if      (idx < 131072) out[idx] = sc[idx];
  else if (idx < 135680) out[idx] = R[idx-131072];
  else if (idx < 137216) out[idx] = t[idx-135680];
}

extern "C" void kernel_launch(void* const* d_in, const int* in_sizes, int n_in,
                              void* d_out, int out_size, void* d_ws, size_t ws_size,
                              hipStream_t stream){
  const float* s      = (const float*)d_in[0];
  const float* z      = (const float*)d_in[1];
  const float* mask   = (const float*)d_in[2];
  const float* ln_s_g = (const float*)d_in[3];
  const float* ln_s_b = (const float*)d_in[4];
  const float* ln_z_g = (const float*)d_in[5];
  const float* ln_z_b = (const float*)d_in[6];
  const float* w_init = (const float*)d_in[7];
  const float* b_init = (const float*)d_in[8];
  const float* ln_ipa_g = (const float*)d_in[9];
  const float* ln_ipa_b = (const float*)d_in[10];
  const float* ln_tr_g  = (const float*)d_in[11];
  const float* ln_tr_b  = (const float*)d_in[12];
  const float* wq = (const float*)d_in[13]; const float* bq = (const float*)d_in[14];
  const float* wk = (const float*)d_in[15]; const float* bk = (const float*)d_in[16];
  const float* wv = (const float*)d_in[17]; const float* bv = (const float*)d_in[18];
  const float* wqp = (const float*)d_in[19]; const float* bqp = (const float*)d_in[20];
  const float* wkp = (const float*)d_in[21]; const float* bkp = (const float*)d_in[22];
  const float* wvp = (const float*)d_in[23]; const float* bvp = (const float*)d_in[24];
  const float* wpb = (const float*)d_in[25];
  const float* head_w = (const float*)d_in[26];
  const float* wo = (const float*)d_in[27]; const float* bo = (const float*)d_in[28];
  const float* wt1 = (const float*)d_in[29]; const float* bt1 = (const float*)d_in[30];
  const float* wt2 = (const float*)d_in[31]; const float* bt2 = (const float*)d_in[32];
  const float* wt3 = (const float*)d_in[33]; const float* bt3 = (const float*)d_in[34];
  const float* wbb = (const float*)d_in[35]; const float* bbb = (const float*)d_in[36];

  float* W = (float*)d_ws;
  float* scb   = W + OFF_SC;
  __half*  pbb  = (__half*)(W + OFF_PB);
  float* Pb    = W + OFF_P;
  float* qnb   = W + OFF_QN;
  float* knb   = W + OFF_KN;
  __hip_bfloat16* a16hi = (__hip_bfloat16*)(W + OFF_A16);
  __hip_bfloat16* a16lo = a16hi + 2097152;
  float* catb  = W + OFF_CAT;
  float* s0b   = W + OFF_S0;
  float* Rb    = W + OFF_R;
  float* tb    = W + OFF_T;
  float* gammab= W + OFF_GAMMA;
  float* maskb = W + OFF_MASKB;
  float* bcat  = W + OFF_BCAT;
  __hip_bfloat16* WinitP = (__hip_bfloat16*)(W + OFF_WINITP);
  __hip_bfloat16* Wt1P   = (__hip_bfloat16*)(W + OFF_WT1P);
  __hip_bfloat16* Wt2P   = (__hip_bfloat16*)(W + OFF_WT2P);
  __hip_bfloat16* Wt3P   = (__hip_bfloat16*)(W + OFF_WT3P);
  __hip_bfloat16* WoP    = (__hip_bfloat16*)(W + OFF_WOP);
  __hip_bfloat16* WcatP  = (__hip_bfloat16*)(W + OFF_WCATP);
  float* Qp = W + OFF_QP;
  __hip_bfloat16* Kp = (__hip_bfloat16*)(W + OFF_KP);
  __hip_bfloat16* Vp = (__hip_bfloat16*)(W + OFF_VP);
  __hip_bfloat16* znt = (__hip_bfloat16*)(W + OFF_ZNT);

  k_setup<<<9, 256, 0, stream>>>(bq,bk,bv,bqp,bkp,bvp, head_w, mask, bcat, gammab, maskb, Rb, tb);
  k_pack_cat<<<CSd*NPROJ/256, 256, 0, stream>>>(wq,wk,wv,wqp,wkp,wvp, WcatP);
  k_pack<<<256,  256, 0, stream>>>(w_init, CSd, CSd, WinitP);
  k_pack<<<1536, 256, 0, stream>>>(wo, CATd, CSd, WoP);
  k_pack<<<256,  256, 0, stream>>>(wt1, CSd, CSd, Wt1P);
  k_pack<<<256,  256, 0, stream>>>(wt2, CSd, CSd, Wt2P);
  k_pack<<<256,  256, 0, stream>>>(wt3, CSd, CSd, Wt3P);

  k_addln<<<Lq, 256, 0, stream>>>(s, nullptr, ln_s_g, ln_s_b, s0b);
  k_gemm_mfma<<<dim3(4,8), 256, 0, stream>>>(s0b, CSd, WinitP, CSd, b_init, scb, 0, nullptr);
  k_lnz_pb<<<Lq*Lq/64, 256, 0, stream>>>(z, ln_z_g, ln_z_b, wpb, pbb, znt);

  for (int it=0; it<8; ++it){
    k_gemm_mfma<<<dim3(18,8), 256, 0, stream>>>(scb, CSd, WcatP, NPROJ, bcat, Pb, 0, nullptr);
    k_packqkv<<<3072, 256, 0, stream>>>(Pb, Rb, tb, gammab, Qp, Kp, Vp, qnb, knb);
    k_attn<<<dim3(32,8), 256, 0, stream>>>(Qp, Kp, Vp, qnb, knb, pbb, maskb, gammab, Rb, tb,
                                           a16hi, a16lo, catb);
    k_opair_mfma<<<Lq, 256, 0, stream>>>(a16hi, a16lo, znt, catb);
    k_mega<<<32, 256, 0, stream>>>(scb, catb, WoP, bo, ln_ipa_g, ln_ipa_b,
                                   Wt1P, bt1, Wt2P, bt2, Wt3P, bt3,
                                   ln_tr_g, ln_tr_b, mask, wbb, bbb, Rb, tb);
  }
  k_writeout<<<536, 256, 0, stream>>>(scb, Rb, tb, (float*)d_out);
}